// Round 16
// baseline (432.635 us; speedup 1.0000x reference)
//
#include <hip/hip_runtime.h>
#include <hip/hip_bf16.h>
#include <stdint.h>

// MultiHeadDiffAttention — R16. R15 isolated: fixed-ref softmax DID cut VALU
// (50->33%) but the permlane-asm/union path spilled to scratch (WRITE 20->102MB).
// R16 = R14's exact diffattn (proven register-clean) + ONLY the fixed-reference
// softmax (no max tree / defer / rescale). cvt_bf16 x3 merged into one launch.
// B=2, T=2048, C=1024, H=16, HS=64.

#define T_SEQ 2048

typedef unsigned short u16;
typedef __attribute__((ext_vector_type(8))) short short8;
typedef __attribute__((ext_vector_type(4))) float f32x4;
typedef __attribute__((ext_vector_type(16))) float f32x16;

#define LAMBDA_INIT 0.35550906759096926f
#define ONE_MINUS_LI 0.6444909324090307f
#define SM_SCALE 0.125f
#define LOG2E 1.44269504f

__device__ __forceinline__ u16 f2bf(float f) {
  uint32_t u = __float_as_uint(f);
  return (u16)((u + 0x7FFFu + ((u >> 16) & 1u)) >> 16);
}
__device__ __forceinline__ float b2f(u16 u) {
  return __uint_as_float(((uint32_t)u) << 16);
}
__device__ __forceinline__ short8 ld8(const u16* p) {
  return *reinterpret_cast<const short8*>(p);
}
__device__ __forceinline__ void st8(u16* p, short8 v) {
  *reinterpret_cast<short8*>(p) = v;
}
__device__ __forceinline__ f32x4 mfma16(short8 a, short8 b, f32x4 c) {
  return __builtin_amdgcn_mfma_f32_16x16x32_bf16(a, b, c, 0, 0, 0);
}
__device__ __forceinline__ f32x16 mfma32(short8 a, short8 b, f32x16 c) {
  return __builtin_amdgcn_mfma_f32_32x32x16_bf16(a, b, c, 0, 0, 0);
}
__device__ __forceinline__ uint32_t cvtpk(float lo, float hi_) {
  uint32_t r;
  asm("v_cvt_pk_bf16_f32 %0, %1, %2" : "=v"(r) : "v"(lo), "v"(hi_));
  return r;
}

// ------------- merged elementwise f32 -> bf16 (q,k,v in one launch) -------------
__global__ __launch_bounds__(256) void cvt3_bf16(const float* __restrict__ q,
                                                 const float* __restrict__ k,
                                                 const float* __restrict__ v,
                                                 u16* __restrict__ out, int n) {
  int i = (blockIdx.x * 256 + threadIdx.x) * 4;  // over 3n elems
  const float* src;
  int j = i;
  if (i < n) src = q;
  else if (i < 2 * n) { src = k; j = i - n; }
  else { src = v; j = i - 2 * n; }
  float4 f = *reinterpret_cast<const float4*>(src + j);
  union { u16 u[4]; uint2 v2; } pk;
  pk.u[0] = f2bf(f.x); pk.u[1] = f2bf(f.y); pk.u[2] = f2bf(f.z); pk.u[3] = f2bf(f.w);
  *reinterpret_cast<uint2*>(out + i) = pk.v2;
}

// ------------- transpose + convert: W[K][N] f32 -> WT[N][K] bf16 -------------
__global__ __launch_bounds__(256) void tcvt(const float* __restrict__ W,
                                            u16* __restrict__ WT,
                                            int K, int N, int outRowOff) {
  __shared__ float tile[32][33];
  int n0 = blockIdx.x * 32, k0 = blockIdx.y * 32;
  int tx = threadIdx.x & 31, ty = threadIdx.x >> 5;  // ty 0..7
#pragma unroll
  for (int p = 0; p < 4; ++p)
    tile[ty + 8 * p][tx] = W[(size_t)(k0 + ty + 8 * p) * N + n0 + tx];
  __syncthreads();
#pragma unroll
  for (int p = 0; p < 4; ++p)
    WT[(size_t)(outRowOff + n0 + ty + 8 * p) * K + k0 + tx] = f2bf(tile[tx][ty + 8 * p]);
}

// ---------------- concat two 1024-float biases ----------------
__global__ __launch_bounds__(256) void bias_concat(const float* __restrict__ b1,
                                                   const float* __restrict__ b2,
                                                   float* __restrict__ out) {
  int i = blockIdx.x * 256 + threadIdx.x;  // 0..2047
  out[i] = (i < 1024) ? b1[i] : b2[i - 1024];
}

// ---------------- GEMM: C[M][N] = A[M][K] @ BT[N][K]^T + bias ----------------
// m97 geometry: 128x128 tile, BK=64, 4 waves, global_load_lds width 16.
// EPI 1: bf16 vvT ((b*2048+col)*2048 + t).  EPI 2: f32 [M][N].
// EPI 4 (fused q|k): rows<4096 -> bf16 [M][2048] q1q2; rows>=4096 -> kT layout
//   kT[((b*2+stream)*16+h)][t][d] at Cv+8388608 (stream=col>>10, h=(col>>6)&15).
#define BM 128
#define BN 128
#define BK 64

template <int EPI, bool QK>
__global__ __launch_bounds__(256) void gemm_bt(const u16* __restrict__ A,
                                               const u16* __restrict__ BT,
                                               const float* __restrict__ bias,
                                               void* __restrict__ Cv,
                                               int M, int N, int K) {
  __shared__ __align__(16) u16 As[BM * BK];
  __shared__ __align__(16) u16 Bs[BN * BK];
  int t = threadIdx.x;
  int w = t >> 6, l = t & 63;
  int g = l >> 4, c16 = l & 15;
  int wr = w >> 1, wc = w & 1;
  size_t gm = (size_t)blockIdx.y * BM, gn = (size_t)blockIdx.x * BN;
  if (QK && gm >= 4096) {
    BT += (size_t)2048 * 1024;  // Wk12T follows Wq12T
    bias += 2048;               // biask follows biasq
  }

  f32x4 acc[4][4] = {};

  int srow = l >> 3;       // 0..7 (8 lanes per row, 8 elems each)
  int scol = (l & 7) * 8;  // 0..56
  const u16* Ag = A + (gm + w * 32 + srow) * (size_t)K + scol;
  const u16* Bg = BT + (gn + w * 32 + srow) * (size_t)K + scol;

  for (int kt = 0; kt < K; kt += BK) {
    __syncthreads();
#pragma unroll
    for (int c = 0; c < 4; ++c) {
      __builtin_amdgcn_global_load_lds(
          (const __attribute__((address_space(1))) void*)(Ag + (size_t)(c * 8) * K + kt),
          (__attribute__((address_space(3))) void*)&As[(w * 32 + c * 8) * BK], 16, 0, 0);
      __builtin_amdgcn_global_load_lds(
          (const __attribute__((address_space(1))) void*)(Bg + (size_t)(c * 8) * K + kt),
          (__attribute__((address_space(3))) void*)&Bs[(w * 32 + c * 8) * BK], 16, 0, 0);
    }
    __syncthreads();
#pragma unroll
    for (int kk = 0; kk < 2; ++kk) {
      short8 af[4], bf[4];
#pragma unroll
      for (int m = 0; m < 4; ++m)
        af[m] = *reinterpret_cast<const short8*>(
            &As[(wr * 64 + m * 16 + c16) * BK + kk * 32 + g * 8]);
#pragma unroll
      for (int n = 0; n < 4; ++n)
        bf[n] = *reinterpret_cast<const short8*>(
            &Bs[(wc * 64 + n * 16 + c16) * BK + kk * 32 + g * 8]);
#pragma unroll
      for (int m = 0; m < 4; ++m)
#pragma unroll
        for (int n = 0; n < 4; ++n)
          acc[m][n] = mfma16(af[m], bf[n], acc[m][n]);
    }
  }

#pragma unroll
  for (int m = 0; m < 4; ++m)
#pragma unroll
    for (int n = 0; n < 4; ++n) {
      int row0 = (int)gm + wr * 64 + m * 16 + g * 4;
      int col = (int)gn + wc * 64 + n * 16 + c16;
      float bz = bias[col];
      if (EPI == 1) {
        u16* C = (u16*)Cv;
        int bb = row0 >> 11, tt = row0 & 2047;
        union { u16 u[4]; uint2 v; } pk;
#pragma unroll
        for (int r = 0; r < 4; ++r) pk.u[r] = f2bf(acc[m][n][r] + bz);
        *reinterpret_cast<uint2*>(&C[((size_t)(bb * 2048 + col)) * 2048 + tt]) = pk.v;
      } else if (EPI == 2) {
        float* C = (float*)Cv;
#pragma unroll
        for (int r = 0; r < 4; ++r)
          C[(size_t)(row0 + r) * N + col] = acc[m][n][r] + bz;
      } else {  // EPI == 4: fused q|k
        u16* C = (u16*)Cv;
        if (row0 < 4096) {
#pragma unroll
          for (int r = 0; r < 4; ++r)
            C[(size_t)(row0 + r) * N + col] = f2bf(acc[m][n][r] + bz);
        } else {
          int t0 = row0 - 4096;
          int bb = t0 >> 11, tt = t0 & 2047;
          int str = col >> 10, hh = (col >> 6) & 15, dd = col & 63;
          u16* KT = C + 8388608;
          size_t base = (((size_t)(bb * 2 + str) * 16 + hh) * 2048 + tt) * (size_t)64 + dd;
#pragma unroll
          for (int r = 0; r < 4; ++r) KT[base + (size_t)r * 64] = f2bf(acc[m][n][r] + bz);
        }
      }
    }
}

// ---------------- differential flash attention + fused LN (32x32 swapped) ----
// grid 1024 (1D, XCD-swizzled), block 256 = 4 waves = 2 pairs.
// Pair p covers q-rows [xblk*64 + p*32, +32); wave stream s handles stream s+1.
// Fixed-reference softmax (no running max); R14's register-clean exchange path.
#define KROW 72   // K/V LDS row: 64 elems + 8 pad (144B)
#define YROW 72
__global__ __launch_bounds__(256, 3) void diffattn(
    const u16* __restrict__ q1q2, const u16* __restrict__ kT,
    const u16* __restrict__ vvT, const int* __restrict__ mask,
    const float* __restrict__ lq1, const float* __restrict__ lk1,
    const float* __restrict__ lq2, const float* __restrict__ lk2,
    const float* __restrict__ lnw, const float* __restrict__ lnb,
    u16* __restrict__ yout) {
  // Ks [128 rows = stream*64+key][KROW] = 9216 ; Vs [128 d-rows][KROW] = 9216
  __shared__ __align__(16) u16 smem[18432];
  u16* Ksm = smem;
  u16* Vsm = smem + 9216;
  u16* Ysm = smem;  // epilogue overlay

  int tid = threadIdx.x;
  int w = tid >> 6, l = tid & 63;
  int q = l & 31, hi = l >> 5;
  int pair = w >> 1, stream = w & 1;

  // XCD swizzle: same-(b,h) q-blocks land on one XCD -> K/V L2-local
  int id = blockIdx.x;            // 0..1023
  int j = id & 7, rest = id >> 3;
  int xblk = rest & 31, ygrp = rest >> 5;
  int bh = ygrp * 8 + j;
  int b = bh >> 4, h = bh & 15;
  int qr0 = xblk * 64 + pair * 32;

  // lambda
  float lm1 = lq1[h * 64 + l] * lk1[h * 64 + l];
  float lm2 = lq2[h * 64 + l] * lk2[h * 64 + l];
#pragma unroll
  for (int o = 32; o; o >>= 1) {
    lm1 += __shfl_xor(lm1, o);
    lm2 += __shfl_xor(lm2, o);
  }
  float lam = __expf(lm1) - __expf(lm2) + LAMBDA_INIT;

  int soff = stream * 1024;
  const u16* qrow = q1q2 + (size_t)(b * T_SEQ + qr0 + q) * 2048 + h * 64 + soff + hi * 8;
  short8 qf[4];
#pragma unroll
  for (int c = 0; c < 4; ++c) qf[c] = ld8(qrow + c * 16);

  // fixed-reference softmax in log2 domain; mask folds into scale
  float scale = (mask[b * T_SEQ + qr0 + q] == 0) ? 0.f : (SM_SCALE * LOG2E);

  float Lp = 0.f;
  f32x16 acc[4] = {};

  // ---- coalesced staging (256 threads, 8 ld8/thread, all contiguous) ----
  int koff = tid * 16;                 // 0..4095
  int krw = koff >> 6, kcl = koff & 63;
  const u16* srcK0 = kT + (((size_t)(b * 2 + 0) * 16 + h) * 2048) * 64 + koff;
  const u16* srcK1 = kT + (((size_t)(b * 2 + 1) * 16 + h) * 2048) * 64 + koff;
  u16* dstK0 = &Ksm[krw * KROW + kcl];
  u16* dstK1 = &Ksm[(64 + krw) * KROW + kcl];
  int vd0 = tid >> 1, tcol = (tid & 1) * 32;
  const u16* srcV = vvT + ((size_t)(b * 16 + h) * 128 + vd0) * 2048 + tcol;
  u16* dstV = &Vsm[vd0 * KROW + tcol];

  short8 kpa0, kpa1, kpb0, kpb1, vp0, vp1, vp2, vp3;
  kpa0 = ld8(srcK0); kpa1 = ld8(srcK0 + 8);
  kpb0 = ld8(srcK1); kpb1 = ld8(srcK1 + 8);
  vp0 = ld8(srcV); vp1 = ld8(srcV + 8); vp2 = ld8(srcV + 16); vp3 = ld8(srcV + 24);

  for (int kt = 0; kt < T_SEQ; kt += 64) {
    __syncthreads();  // previous tile's reads complete
    st8(dstK0, kpa0); st8(dstK0 + 8, kpa1);
    st8(dstK1, kpb0); st8(dstK1 + 8, kpb1);
    st8(dstV, vp0); st8(dstV + 8, vp1); st8(dstV + 16, vp2); st8(dstV + 24, vp3);
    __syncthreads();  // tile staged
    if (kt + 64 < T_SEQ) {  // prefetch next tile (consumed NEXT iter)
      size_t ko = (size_t)(kt + 64) * 64;
      kpa0 = ld8(srcK0 + ko); kpa1 = ld8(srcK0 + ko + 8);
      kpb0 = ld8(srcK1 + ko); kpb1 = ld8(srcK1 + ko + 8);
      const u16* nv = srcV + kt + 64;
      vp0 = ld8(nv); vp1 = ld8(nv + 8); vp2 = ld8(nv + 16); vp3 = ld8(nv + 24);
    }

#pragma unroll
    for (int st = 0; st < 2; ++st) {
      const u16* kbase = &Ksm[(stream * 64 + st * 32 + q) * KROW + hi * 8];
      short8 kf[4];
#pragma unroll
      for (int c = 0; c < 4; ++c) kf[c] = ld8(kbase + c * 16);

      f32x16 s = {};
#pragma unroll
      for (int c = 0; c < 4; ++c) s = mfma32(kf[c], qf[c], s);

      // p = exp2(s*scale)  (no max subtraction: |s*scale| << exp2 range)
      float p[16];
#pragma unroll
      for (int r = 0; r < 16; ++r) p[r] = exp2f(s[r] * scale);
      float s8[8], s4[4];
#pragma unroll
      for (int i = 0; i < 8; ++i) s8[i] = p[i] + p[i + 8];
#pragma unroll
      for (int i = 0; i < 4; ++i) s4[i] = s8[i] + s8[i + 4];
      Lp += (s4[0] + s4[1]) + (s4[2] + s4[3]);

      // P^T B-frags in-register (R14's register-clean exchange)
      uint32_t a1 = cvtpk(p[0], p[1]), a2 = cvtpk(p[2], p[3]);
      uint32_t b1 = cvtpk(p[4], p[5]), b2 = cvtpk(p[6], p[7]);
      uint32_t c1 = cvtpk(p[8], p[9]), c2 = cvtpk(p[10], p[11]);
      uint32_t d1 = cvtpk(p[12], p[13]), d2 = cvtpk(p[14], p[15]);
      uint32_t sa1 = (uint32_t)__shfl_xor((int)a1, 32), sa2 = (uint32_t)__shfl_xor((int)a2, 32);
      uint32_t sb1 = (uint32_t)__shfl_xor((int)b1, 32), sb2 = (uint32_t)__shfl_xor((int)b2, 32);
      uint32_t sc1 = (uint32_t)__shfl_xor((int)c1, 32), sc2 = (uint32_t)__shfl_xor((int)c2, 32);
      uint32_t sd1 = (uint32_t)__shfl_xor((int)d1, 32), sd2 = (uint32_t)__shfl_xor((int)d2, 32);
      union { uint32_t u[4]; short8 s8v; } pu0, pu1;
      pu0.u[0] = hi ? sb1 : a1;  pu0.u[1] = hi ? sb2 : a2;
      pu0.u[2] = hi ? b1 : sa1;  pu0.u[3] = hi ? b2 : sa2;
      pu1.u[0] = hi ? sd1 : c1;  pu1.u[1] = hi ? sd2 : c2;
      pu1.u[2] = hi ? d1 : sc1;  pu1.u[3] = hi ? d2 : sc2;
      short8 pf0 = pu0.s8v, pf1 = pu1.s8v;

#pragma unroll
      for (int d = 0; d < 4; ++d) {
        const u16* vb0 = &Vsm[(d * 32 + q) * KROW + st * 32 + hi * 8];
        short8 vf0 = ld8(vb0);
        short8 vf1 = ld8(vb0 + 16);
        acc[d] = mfma32(vf0, pf0, acc[d]);
        acc[d] = mfma32(vf1, pf1, acc[d]);
      }
    }
  }

  float L = Lp + __shfl_xor(Lp, 32);
  float inv = 1.f / L;
  __syncthreads();  // staging dead -> Ysm overlay safe
  if (stream == 1) {
    u16* yrow = &Ysm[(pair * 64 + l) * YROW];
#pragma unroll
    for (int d = 0; d < 4; ++d) {
      union { uint32_t u[8]; short8 v[2]; } pk;
#pragma unroll
      for (int i = 0; i < 8; ++i)
        pk.u[i] = cvtpk(acc[d][2 * i] * inv, acc[d][2 * i + 1] * inv);
      st8(yrow + d * 16, pk.v[0]);
      st8(yrow + d * 16 + 8, pk.v[1]);
    }
  }
  __syncthreads();
  if (stream == 0) {
    const u16* yrow = &Ysm[(pair * 64 + l) * YROW];
    float y[4][16];
#pragma unroll
    for (int d = 0; d < 4; ++d) {
      short8 y2a = ld8(yrow + d * 16);
      short8 y2b = ld8(yrow + d * 16 + 8);
#pragma unroll
      for (int i = 0; i < 8; ++i) {
        y[d][i] = acc[d][i] * inv - lam * b2f((u16)y2a[i]);
        y[d][8 + i] = acc[d][8 + i] * inv - lam * b2f((u16)y2b[i]);
      }
    }
    float sm = 0.f;
#pragma unroll
    for (int d = 0; d < 4; ++d)
#pragma unroll
      for (int r = 0; r < 16; ++r) sm += y[d][r];
    sm += __shfl_xor(sm, 32);
    float u = sm * (1.f / 128.f);
    float var = 0.f;
#pragma unroll
    for (int d = 0; d < 4; ++d)
#pragma unroll
      for (int r = 0; r < 16; ++r) { float dd = y[d][r] - u; var += dd * dd; }
    var += __shfl_xor(var, 32);
    float rstd = rsqrtf(var * (1.f / 128.f) + 1e-12f);

    size_t orow = (size_t)(b * T_SEQ + qr0 + q) * 2048 + h * 128;
#pragma unroll
    for (int d = 0; d < 4; ++d)
#pragma unroll
      for (int rr = 0; rr < 4; ++rr) {
        int base = d * 32 + 8 * rr + 4 * hi;
        union { u16 u[4]; uint2 v; } o;
#pragma unroll
        for (int i = 0; i < 4; ++i) {
          float yv = (lnw[base + i] * ((y[d][rr * 4 + i] - u) * rstd) + lnb[base + i]) *
                     ONE_MINUS_LI;
          o.u[i] = f2bf(yv);
        }
        *reinterpret_cast<uint2*>(&yout[orow + base]) = o.v;
      }
  }
}

// ---------------- host ----------------
extern "C" void kernel_launch(void* const* d_in, const int* in_sizes, int n_in,
                              void* d_out, int out_size, void* d_ws, size_t ws_size,
                              hipStream_t stream) {
  (void)in_sizes; (void)n_in; (void)out_size; (void)ws_size;
  const float* q   = (const float*)d_in[0];
  const float* k   = (const float*)d_in[1];
  const float* v   = (const float*)d_in[2];
  const int* maskp = (const int*)d_in[3];
  const float* Wq1 = (const float*)d_in[4];
  const float* bq1 = (const float*)d_in[5];
  const float* Wq2 = (const float*)d_in[6];
  const float* bq2 = (const float*)d_in[7];
  const float* Wk1 = (const float*)d_in[8];
  const float* bk1 = (const float*)d_in[9];
  const float* Wk2 = (const float*)d_in[10];
  const float* bk2 = (const float*)d_in[11];
  const float* Wv  = (const float*)d_in[12];
  const float* bv  = (const float*)d_in[13];
  const float* Wc  = (const float*)d_in[14];
  const float* bc  = (const float*)d_in[15];
  const float* lnw = (const float*)d_in[16];
  const float* lnb = (const float*)d_in[17];
  const float* lq1 = (const float*)d_in[18];
  const float* lk1 = (const float*)d_in[19];
  const float* lq2 = (const float*)d_in[20];
  const float* lk2 = (const float*)d_in[21];

  char* ws = (char*)d_ws;
  u16* qb     = (u16*)(ws + 0);          // qb|kb|vb contiguous (24MB)
  u16* Wq12T  = (u16*)(ws + 25165824);   // Wk12T contiguous after
  u16* WvT    = (u16*)(ws + 33554432);
  u16* WcT    = (u16*)(ws + 37748736);
  float* biasq = (float*)(ws + 41943040);  // biask contiguous after
  u16* q1q2   = (u16*)(ws + 41959424);   // kT contiguous after (+8388608 elems)
  u16* kT     = (u16*)(ws + 58736640);
  u16* vvT    = (u16*)(ws + 75513856);
  u16* yb     = (u16*)(ws + 0);  // alias qb+kb (16MB; both dead before attention)
  u16* vb     = (u16*)(ws + 16777216);
  u16* Wk12T  = (u16*)(ws + 29360128);
  float* biask = (float*)(ws + 41951232);

  const int NELEM = 2 * T_SEQ * 1024;  // 4,194,304

  cvt3_bf16<<<12288, 256, 0, stream>>>(q, k, v, qb, NELEM);

  tcvt<<<dim3(32, 32), 256, 0, stream>>>(Wq1, Wq12T, 1024, 1024, 0);
  tcvt<<<dim3(32, 32), 256, 0, stream>>>(Wq2, Wq12T, 1024, 1024, 1024);
  tcvt<<<dim3(32, 32), 256, 0, stream>>>(Wk1, Wk12T, 1024, 1024, 0);
  tcvt<<<dim3(32, 32), 256, 0, stream>>>(Wk2, Wk12T, 1024, 1024, 1024);
  tcvt<<<dim3(64, 32), 256, 0, stream>>>(Wv, WvT, 1024, 2048, 0);
  tcvt<<<dim3(32, 64), 256, 0, stream>>>(Wc, WcT, 2048, 1024, 0);

  bias_concat<<<8, 256, 0, stream>>>(bq1, bq2, biasq);
  bias_concat<<<8, 256, 0, stream>>>(bk1, bk2, biask);

  // fused q-proj + k-proj: M=8192; q-half -> q1q2 (bf16 MN), k-half -> kT layout
  gemm_bt<4, true><<<dim3(16, 64), 256, 0, stream>>>(qb, Wq12T, biasq, q1q2,
                                                     8192, 2048, 1024);
  gemm_bt<1, false><<<dim3(16, 32), 256, 0, stream>>>(vb, WvT, bv, vvT, 4096, 2048, 1024);

  diffattn<<<1024, 256, 0, stream>>>(q1q2, kT, vvT, maskp,
                                     lq1, lk1, lq2, lk2, lnw, lnb, yb);

  gemm_bt<2, false><<<dim3(8, 32), 256, 0, stream>>>(yb, WcT, bc, d_out, 4096, 1024, 2048);
}

// Round 17
// 325.174 us; speedup vs baseline: 1.3305x; 1.3305x over previous
//
#include <hip/hip_runtime.h>
#include <hip/hip_bf16.h>
#include <stdint.h>

// MultiHeadDiffAttention — R17 = exact revert to R14 (proven best: 324.9us).
// R15 (permlane union), R16 (max-tree removal) both triggered hipcc regalloc
// spills (WRITE_SIZE 20->102/425MB): the defer-max branch acts as an accidental
// scheduling fence keeping live ranges short. diffattn loop body is at a
// source-level stability boundary — do not perturb.
// B=2, T=2048, C=1024, H=16, HS=64.

#define T_SEQ 2048

typedef unsigned short u16;
typedef __attribute__((ext_vector_type(8))) short short8;
typedef __attribute__((ext_vector_type(4))) float f32x4;
typedef __attribute__((ext_vector_type(16))) float f32x16;

#define LAMBDA_INIT 0.35550906759096926f
#define ONE_MINUS_LI 0.6444909324090307f
#define SM_SCALE 0.125f
#define LOG2E 1.44269504f

__device__ __forceinline__ u16 f2bf(float f) {
  uint32_t u = __float_as_uint(f);
  return (u16)((u + 0x7FFFu + ((u >> 16) & 1u)) >> 16);
}
__device__ __forceinline__ float b2f(u16 u) {
  return __uint_as_float(((uint32_t)u) << 16);
}
__device__ __forceinline__ short8 ld8(const u16* p) {
  return *reinterpret_cast<const short8*>(p);
}
__device__ __forceinline__ void st8(u16* p, short8 v) {
  *reinterpret_cast<short8*>(p) = v;
}
__device__ __forceinline__ f32x4 mfma16(short8 a, short8 b, f32x4 c) {
  return __builtin_amdgcn_mfma_f32_16x16x32_bf16(a, b, c, 0, 0, 0);
}
__device__ __forceinline__ f32x16 mfma32(short8 a, short8 b, f32x16 c) {
  return __builtin_amdgcn_mfma_f32_32x32x16_bf16(a, b, c, 0, 0, 0);
}
__device__ __forceinline__ uint32_t cvtpk(float lo, float hi_) {
  uint32_t r;
  asm("v_cvt_pk_bf16_f32 %0, %1, %2" : "=v"(r) : "v"(lo), "v"(hi_));
  return r;
}

// ---------------- elementwise f32 -> bf16 ----------------
__global__ __launch_bounds__(256) void cvt_bf16(const float* __restrict__ in,
                                                u16* __restrict__ out, int n) {
  int i = (blockIdx.x * 256 + threadIdx.x) * 4;
  if (i >= n) return;
  float4 f = *reinterpret_cast<const float4*>(in + i);
  union { u16 u[4]; uint2 v; } pk;
  pk.u[0] = f2bf(f.x); pk.u[1] = f2bf(f.y); pk.u[2] = f2bf(f.z); pk.u[3] = f2bf(f.w);
  *reinterpret_cast<uint2*>(out + i) = pk.v;
}

// ------------- transpose + convert: W[K][N] f32 -> WT[N][K] bf16 -------------
__global__ __launch_bounds__(256) void tcvt(const float* __restrict__ W,
                                            u16* __restrict__ WT,
                                            int K, int N, int outRowOff) {
  __shared__ float tile[32][33];
  int n0 = blockIdx.x * 32, k0 = blockIdx.y * 32;
  int tx = threadIdx.x & 31, ty = threadIdx.x >> 5;  // ty 0..7
#pragma unroll
  for (int p = 0; p < 4; ++p)
    tile[ty + 8 * p][tx] = W[(size_t)(k0 + ty + 8 * p) * N + n0 + tx];
  __syncthreads();
#pragma unroll
  for (int p = 0; p < 4; ++p)
    WT[(size_t)(outRowOff + n0 + ty + 8 * p) * K + k0 + tx] = f2bf(tile[tx][ty + 8 * p]);
}

// ---------------- concat two 1024-float biases ----------------
__global__ __launch_bounds__(256) void bias_concat(const float* __restrict__ b1,
                                                   const float* __restrict__ b2,
                                                   float* __restrict__ out) {
  int i = blockIdx.x * 256 + threadIdx.x;  // 0..2047
  out[i] = (i < 1024) ? b1[i] : b2[i - 1024];
}

// ---------------- GEMM: C[M][N] = A[M][K] @ BT[N][K]^T + bias ----------------
// m97 geometry: 128x128 tile, BK=64, 4 waves, global_load_lds width 16.
// EPI 1: bf16 vvT ((b*2048+col)*2048 + t).  EPI 2: f32 [M][N].
// EPI 4 (fused q|k): rows<4096 -> bf16 [M][2048] q1q2; rows>=4096 -> kT layout
//   kT[((b*2+stream)*16+h)][t][d] at Cv+8388608 (stream=col>>10, h=(col>>6)&15).
#define BM 128
#define BN 128
#define BK 64

template <int EPI, bool QK>
__global__ __launch_bounds__(256) void gemm_bt(const u16* __restrict__ A,
                                               const u16* __restrict__ BT,
                                               const float* __restrict__ bias,
                                               void* __restrict__ Cv,
                                               int M, int N, int K) {
  __shared__ __align__(16) u16 As[BM * BK];
  __shared__ __align__(16) u16 Bs[BN * BK];
  int t = threadIdx.x;
  int w = t >> 6, l = t & 63;
  int g = l >> 4, c16 = l & 15;
  int wr = w >> 1, wc = w & 1;
  size_t gm = (size_t)blockIdx.y * BM, gn = (size_t)blockIdx.x * BN;
  if (QK && gm >= 4096) {
    BT += (size_t)2048 * 1024;  // Wk12T follows Wq12T
    bias += 2048;               // biask follows biasq
  }

  f32x4 acc[4][4] = {};

  int srow = l >> 3;       // 0..7 (8 lanes per row, 8 elems each)
  int scol = (l & 7) * 8;  // 0..56
  const u16* Ag = A + (gm + w * 32 + srow) * (size_t)K + scol;
  const u16* Bg = BT + (gn + w * 32 + srow) * (size_t)K + scol;

  for (int kt = 0; kt < K; kt += BK) {
    __syncthreads();
#pragma unroll
    for (int c = 0; c < 4; ++c) {
      __builtin_amdgcn_global_load_lds(
          (const __attribute__((address_space(1))) void*)(Ag + (size_t)(c * 8) * K + kt),
          (__attribute__((address_space(3))) void*)&As[(w * 32 + c * 8) * BK], 16, 0, 0);
      __builtin_amdgcn_global_load_lds(
          (const __attribute__((address_space(1))) void*)(Bg + (size_t)(c * 8) * K + kt),
          (__attribute__((address_space(3))) void*)&Bs[(w * 32 + c * 8) * BK], 16, 0, 0);
    }
    __syncthreads();
#pragma unroll
    for (int kk = 0; kk < 2; ++kk) {
      short8 af[4], bf[4];
#pragma unroll
      for (int m = 0; m < 4; ++m)
        af[m] = *reinterpret_cast<const short8*>(
            &As[(wr * 64 + m * 16 + c16) * BK + kk * 32 + g * 8]);
#pragma unroll
      for (int n = 0; n < 4; ++n)
        bf[n] = *reinterpret_cast<const short8*>(
            &Bs[(wc * 64 + n * 16 + c16) * BK + kk * 32 + g * 8]);
#pragma unroll
      for (int m = 0; m < 4; ++m)
#pragma unroll
        for (int n = 0; n < 4; ++n)
          acc[m][n] = mfma16(af[m], bf[n], acc[m][n]);
    }
  }

#pragma unroll
  for (int m = 0; m < 4; ++m)
#pragma unroll
    for (int n = 0; n < 4; ++n) {
      int row0 = (int)gm + wr * 64 + m * 16 + g * 4;
      int col = (int)gn + wc * 64 + n * 16 + c16;
      float bz = bias[col];
      if (EPI == 1) {
        u16* C = (u16*)Cv;
        int bb = row0 >> 11, tt = row0 & 2047;
        union { u16 u[4]; uint2 v; } pk;
#pragma unroll
        for (int r = 0; r < 4; ++r) pk.u[r] = f2bf(acc[m][n][r] + bz);
        *reinterpret_cast<uint2*>(&C[((size_t)(bb * 2048 + col)) * 2048 + tt]) = pk.v;
      } else if (EPI == 2) {
        float* C = (float*)Cv;
#pragma unroll
        for (int r = 0; r < 4; ++r)
          C[(size_t)(row0 + r) * N + col] = acc[m][n][r] + bz;
      } else {  // EPI == 4: fused q|k
        u16* C = (u16*)Cv;
        if (row0 < 4096) {
#pragma unroll
          for (int r = 0; r < 4; ++r)
            C[(size_t)(row0 + r) * N + col] = f2bf(acc[m][n][r] + bz);
        } else {
          int t0 = row0 - 4096;
          int bb = t0 >> 11, tt = t0 & 2047;
          int str = col >> 10, hh = (col >> 6) & 15, dd = col & 63;
          u16* KT = C + 8388608;
          size_t base = (((size_t)(bb * 2 + str) * 16 + hh) * 2048 + tt) * (size_t)64 + dd;
#pragma unroll
          for (int r = 0; r < 4; ++r) KT[base + (size_t)r * 64] = f2bf(acc[m][n][r] + bz);
        }
      }
    }
}

// ---------------- differential flash attention + fused LN (32x32 swapped) ----
// grid 1024 (1D, XCD-swizzled), block 256 = 4 waves = 2 pairs.
// Pair p covers q-rows [xblk*64 + p*32, +32); wave stream s handles stream s+1.
// 64-key staged tiles, 2-barrier R8/R12-proven staging, COALESCED sources:
// K from kT (contiguous 8KB/stream/tile), V along t (64B/thread contiguous).
#define KROW 72   // K/V LDS row: 64 elems + 8 pad (144B)
#define YROW 72
__global__ __launch_bounds__(256, 3) void diffattn(
    const u16* __restrict__ q1q2, const u16* __restrict__ kT,
    const u16* __restrict__ vvT, const int* __restrict__ mask,
    const float* __restrict__ lq1, const float* __restrict__ lk1,
    const float* __restrict__ lq2, const float* __restrict__ lk2,
    const float* __restrict__ lnw, const float* __restrict__ lnb,
    u16* __restrict__ yout) {
  // Ks [128 rows = stream*64+key][KROW] = 9216 ; Vs [128 d-rows][KROW] = 9216
  __shared__ __align__(16) u16 smem[18432];
  u16* Ksm = smem;
  u16* Vsm = smem + 9216;
  u16* Ysm = smem;  // epilogue overlay

  int tid = threadIdx.x;
  int w = tid >> 6, l = tid & 63;
  int q = l & 31, hi = l >> 5;
  int pair = w >> 1, stream = w & 1;

  // XCD swizzle: same-(b,h) q-blocks land on one XCD -> K/V L2-local
  int id = blockIdx.x;            // 0..1023
  int j = id & 7, rest = id >> 3;
  int xblk = rest & 31, ygrp = rest >> 5;
  int bh = ygrp * 8 + j;
  int b = bh >> 4, h = bh & 15;
  int qr0 = xblk * 64 + pair * 32;

  // lambda
  float lm1 = lq1[h * 64 + l] * lk1[h * 64 + l];
  float lm2 = lq2[h * 64 + l] * lk2[h * 64 + l];
#pragma unroll
  for (int o = 32; o; o >>= 1) {
    lm1 += __shfl_xor(lm1, o);
    lm2 += __shfl_xor(lm2, o);
  }
  float lam = __expf(lm1) - __expf(lm2) + LAMBDA_INIT;

  int soff = stream * 1024;
  const u16* qrow = q1q2 + (size_t)(b * T_SEQ + qr0 + q) * 2048 + h * 64 + soff + hi * 8;
  short8 qf[4];
#pragma unroll
  for (int c = 0; c < 4; ++c) qf[c] = ld8(qrow + c * 16);

  // softmax in log2 domain; mask folds into scale (0 -> uniform softmax)
  float scale = (mask[b * T_SEQ + qr0 + q] == 0) ? 0.f : (SM_SCALE * LOG2E);

  float M = -INFINITY, Lp = 0.f;
  f32x16 acc[4] = {};

  // ---- coalesced staging (256 threads, 8 ld8/thread, all contiguous) ----
  // K: per stream, thread t covers 16 contiguous elems at offset t*16 of the
  //    64x64 kT tile (8KB contiguous per tile).
  int koff = tid * 16;                 // 0..4095
  int krw = koff >> 6, kcl = koff & 63;
  const u16* srcK0 = kT + (((size_t)(b * 2 + 0) * 16 + h) * 2048) * 64 + koff;
  const u16* srcK1 = kT + (((size_t)(b * 2 + 1) * 16 + h) * 2048) * 64 + koff;
  u16* dstK0 = &Ksm[krw * KROW + kcl];
  u16* dstK1 = &Ksm[(64 + krw) * KROW + kcl];
  // V: thread t covers 32 contiguous t-elems of d-row (t>>1) at col (t&1)*32.
  int vd0 = tid >> 1, tcol = (tid & 1) * 32;
  const u16* srcV = vvT + ((size_t)(b * 16 + h) * 128 + vd0) * 2048 + tcol;
  u16* dstV = &Vsm[vd0 * KROW + tcol];

  short8 kpa0, kpa1, kpb0, kpb1, vp0, vp1, vp2, vp3;
  kpa0 = ld8(srcK0); kpa1 = ld8(srcK0 + 8);
  kpb0 = ld8(srcK1); kpb1 = ld8(srcK1 + 8);
  vp0 = ld8(srcV); vp1 = ld8(srcV + 8); vp2 = ld8(srcV + 16); vp3 = ld8(srcV + 24);

  for (int kt = 0; kt < T_SEQ; kt += 64) {
    __syncthreads();  // previous tile's reads complete
    st8(dstK0, kpa0); st8(dstK0 + 8, kpa1);
    st8(dstK1, kpb0); st8(dstK1 + 8, kpb1);
    st8(dstV, vp0); st8(dstV + 8, vp1); st8(dstV + 16, vp2); st8(dstV + 24, vp3);
    __syncthreads();  // tile staged
    if (kt + 64 < T_SEQ) {  // prefetch next tile (consumed NEXT iter)
      size_t ko = (size_t)(kt + 64) * 64;
      kpa0 = ld8(srcK0 + ko); kpa1 = ld8(srcK0 + ko + 8);
      kpb0 = ld8(srcK1 + ko); kpb1 = ld8(srcK1 + ko + 8);
      const u16* nv = srcV + kt + 64;
      vp0 = ld8(nv); vp1 = ld8(nv + 8); vp2 = ld8(nv + 16); vp3 = ld8(nv + 24);
    }

#pragma unroll
    for (int st = 0; st < 2; ++st) {
      const u16* kbase = &Ksm[(stream * 64 + st * 32 + q) * KROW + hi * 8];
      short8 kf[4];
#pragma unroll
      for (int c = 0; c < 4; ++c) kf[c] = ld8(kbase + c * 16);

      f32x16 s = {};
#pragma unroll
      for (int c = 0; c < 4; ++c) s = mfma32(kf[c], qf[c], s);

      // tile max: max3-fusable tree + cross-half
      float m0 = fmaxf(fmaxf(s[0], s[1]), s[2]);
      float m1 = fmaxf(fmaxf(s[3], s[4]), s[5]);
      float m2 = fmaxf(fmaxf(s[6], s[7]), s[8]);
      float m3 = fmaxf(fmaxf(s[9], s[10]), s[11]);
      float m4 = fmaxf(fmaxf(s[12], s[13]), s[14]);
      float ma = fmaxf(fmaxf(m0, m1), m2);
      float mb = fmaxf(fmaxf(m3, m4), s[15]);
      float rm = fmaxf(ma, mb);
      rm = fmaxf(rm, __shfl_xor(rm, 32));
      float tm = rm * scale;

      // defer-max (log2 units: 11.5 ~ e^8); M synced across halves
      if (!__all(tm - M <= 11.5f)) {
        float Mn = fmaxf(M, tm);
        float a = exp2f(M - Mn);
        Lp *= a;
#pragma unroll
        for (int d = 0; d < 4; ++d) acc[d] *= a;
        M = Mn;
      }

      // p = exp2(s*scale - M); lane-local partial sum (combined once at end)
      float p[16];
#pragma unroll
      for (int r = 0; r < 16; ++r) p[r] = exp2f(__builtin_fmaf(s[r], scale, -M));
      float s8[8], s4[4];
#pragma unroll
      for (int i = 0; i < 8; ++i) s8[i] = p[i] + p[i + 8];
#pragma unroll
      for (int i = 0; i < 4; ++i) s4[i] = s8[i] + s8[i + 4];
      Lp += (s4[0] + s4[1]) + (s4[2] + s4[3]);

      // P^T B-frags in-register
      uint32_t a1 = cvtpk(p[0], p[1]), a2 = cvtpk(p[2], p[3]);
      uint32_t b1 = cvtpk(p[4], p[5]), b2 = cvtpk(p[6], p[7]);
      uint32_t c1 = cvtpk(p[8], p[9]), c2 = cvtpk(p[10], p[11]);
      uint32_t d1 = cvtpk(p[12], p[13]), d2 = cvtpk(p[14], p[15]);
      uint32_t sa1 = (uint32_t)__shfl_xor((int)a1, 32), sa2 = (uint32_t)__shfl_xor((int)a2, 32);
      uint32_t sb1 = (uint32_t)__shfl_xor((int)b1, 32), sb2 = (uint32_t)__shfl_xor((int)b2, 32);
      uint32_t sc1 = (uint32_t)__shfl_xor((int)c1, 32), sc2 = (uint32_t)__shfl_xor((int)c2, 32);
      uint32_t sd1 = (uint32_t)__shfl_xor((int)d1, 32), sd2 = (uint32_t)__shfl_xor((int)d2, 32);
      union { uint32_t u[4]; short8 s8v; } pu0, pu1;
      pu0.u[0] = hi ? sb1 : a1;  pu0.u[1] = hi ? sb2 : a2;
      pu0.u[2] = hi ? b1 : sa1;  pu0.u[3] = hi ? b2 : sa2;
      pu1.u[0] = hi ? sd1 : c1;  pu1.u[1] = hi ? sd2 : c2;
      pu1.u[2] = hi ? d1 : sc1;  pu1.u[3] = hi ? d2 : sc2;
      short8 pf0 = pu0.s8v, pf1 = pu1.s8v;

#pragma unroll
      for (int d = 0; d < 4; ++d) {
        const u16* vb0 = &Vsm[(d * 32 + q) * KROW + st * 32 + hi * 8];
        short8 vf0 = ld8(vb0);
        short8 vf1 = ld8(vb0 + 16);
        acc[d] = mfma32(vf0, pf0, acc[d]);
        acc[d] = mfma32(vf1, pf1, acc[d]);
      }
    }
  }

  float L = Lp + __shfl_xor(Lp, 32);
  float inv = 1.f / L;
  __syncthreads();  // staging dead -> Ysm overlay safe
  if (stream == 1) {
    u16* yrow = &Ysm[(pair * 64 + l) * YROW];
#pragma unroll
    for (int d = 0; d < 4; ++d) {
      union { uint32_t u[8]; short8 v[2]; } pk;
#pragma unroll
      for (int i = 0; i < 8; ++i)
        pk.u[i] = cvtpk(acc[d][2 * i] * inv, acc[d][2 * i + 1] * inv);
      st8(yrow + d * 16, pk.v[0]);
      st8(yrow + d * 16 + 8, pk.v[1]);
    }
  }
  __syncthreads();
  if (stream == 0) {
    const u16* yrow = &Ysm[(pair * 64 + l) * YROW];
    float y[4][16];
#pragma unroll
    for (int d = 0; d < 4; ++d) {
      short8 y2a = ld8(yrow + d * 16);
      short8 y2b = ld8(yrow + d * 16 + 8);
#pragma unroll
      for (int i = 0; i < 8; ++i) {
        y[d][i] = acc[d][i] * inv - lam * b2f((u16)y2a[i]);
        y[d][8 + i] = acc[d][8 + i] * inv - lam * b2f((u16)y2b[i]);
      }
    }
    float sm = 0.f;
#pragma unroll
    for (int d = 0; d < 4; ++d)
#pragma unroll
      for (int r = 0; r < 16; ++r) sm += y[d][r];
    sm += __shfl_xor(sm, 32);
    float u = sm * (1.f / 128.f);
    float var = 0.f;
#pragma unroll
    for (int d = 0; d < 4; ++d)
#pragma unroll
      for (int r = 0; r < 16; ++r) { float dd = y[d][r] - u; var += dd * dd; }
    var += __shfl_xor(var, 32);
    float rstd = rsqrtf(var * (1.f / 128.f) + 1e-12f);

    size_t orow = (size_t)(b * T_SEQ + qr0 + q) * 2048 + h * 128;
#pragma unroll
    for (int d = 0; d < 4; ++d)
#pragma unroll
      for (int rr = 0; rr < 4; ++rr) {
        int base = d * 32 + 8 * rr + 4 * hi;
        union { u16 u[4]; uint2 v; } o;
#pragma unroll
        for (int i = 0; i < 4; ++i) {
          float yv = (lnw[base + i] * ((y[d][rr * 4 + i] - u) * rstd) + lnb[base + i]) *
                     ONE_MINUS_LI;
          o.u[i] = f2bf(yv);
        }
        *reinterpret_cast<uint2*>(&yout[orow + base]) = o.v;
      }
  }
}

// ---------------- host ----------------
extern "C" void kernel_launch(void* const* d_in, const int* in_sizes, int n_in,
                              void* d_out, int out_size, void* d_ws, size_t ws_size,
                              hipStream_t stream) {
  (void)in_sizes; (void)n_in; (void)out_size; (void)ws_size;
  const float* q   = (const float*)d_in[0];
  const float* k   = (const float*)d_in[1];
  const float* v   = (const float*)d_in[2];
  const int* maskp = (const int*)d_in[3];
  const float* Wq1 = (const float*)d_in[4];
  const float* bq1 = (const float*)d_in[5];
  const float* Wq2 = (const float*)d_in[6];
  const float* bq2 = (const float*)d_in[7];
  const float* Wk1 = (const float*)d_in[8];
  const float* bk1 = (const float*)d_in[9];
  const float* Wk2 = (const float*)d_in[10];
  const float* bk2 = (const float*)d_in[11];
  const float* Wv  = (const float*)d_in[12];
  const float* bv  = (const float*)d_in[13];
  const float* Wc  = (const float*)d_in[14];
  const float* bc  = (const float*)d_in[15];
  const float* lnw = (const float*)d_in[16];
  const float* lnb = (const float*)d_in[17];
  const float* lq1 = (const float*)d_in[18];
  const float* lk1 = (const float*)d_in[19];
  const float* lq2 = (const float*)d_in[20];
  const float* lk2 = (const float*)d_in[21];

  char* ws = (char*)d_ws;
  u16* qb     = (u16*)(ws + 0);          // rows 0..4095 ; kb continues at 4096
  u16* kb     = (u16*)(ws + 8388608);
  u16* vb     = (u16*)(ws + 16777216);
  u16* Wq12T  = (u16*)(ws + 25165824);   // Wk12T contiguous after
  u16* Wk12T  = (u16*)(ws + 29360128);
  u16* WvT    = (u16*)(ws + 33554432);
  u16* WcT    = (u16*)(ws + 37748736);
  float* biasq = (float*)(ws + 41943040);  // biask contiguous after
  float* biask = (float*)(ws + 41951232);
  u16* q1q2   = (u16*)(ws + 41959424);   // kT contiguous after (+8388608 elems)
  u16* kT     = (u16*)(ws + 58736640);
  u16* vvT    = (u16*)(ws + 75513856);
  u16* yb     = (u16*)(ws + 0);  // alias qb+kb (16MB; both dead before attention)

  const int NELEM = 2 * T_SEQ * 1024;  // 4,194,304

  cvt_bf16<<<4096, 256, 0, stream>>>(q, qb, NELEM);
  cvt_bf16<<<4096, 256, 0, stream>>>(k, kb, NELEM);
  cvt_bf16<<<4096, 256, 0, stream>>>(v, vb, NELEM);

  tcvt<<<dim3(32, 32), 256, 0, stream>>>(Wq1, Wq12T, 1024, 1024, 0);
  tcvt<<<dim3(32, 32), 256, 0, stream>>>(Wq2, Wq12T, 1024, 1024, 1024);
  tcvt<<<dim3(32, 32), 256, 0, stream>>>(Wk1, Wk12T, 1024, 1024, 0);
  tcvt<<<dim3(32, 32), 256, 0, stream>>>(Wk2, Wk12T, 1024, 1024, 1024);
  tcvt<<<dim3(64, 32), 256, 0, stream>>>(Wv, WvT, 1024, 2048, 0);
  tcvt<<<dim3(32, 64), 256, 0, stream>>>(Wc, WcT, 2048, 1024, 0);

  bias_concat<<<8, 256, 0, stream>>>(bq1, bq2, biasq);
  bias_concat<<<8, 256, 0, stream>>>(bk1, bk2, biask);

  // fused q-proj + k-proj: M=8192; q-half -> q1q2 (bf16 MN), k-half -> kT layout
  gemm_bt<4, true><<<dim3(16, 64), 256, 0, stream>>>(qb, Wq12T, biasq, q1q2,
                                                     8192, 2048, 1024);
  gemm_bt<1, false><<<dim3(16, 32), 256, 0, stream>>>(vb, WvT, bv, vvT, 4096, 2048, 1024);

  diffattn<<<1024, 256, 0, stream>>>(q1q2, kT, vvT, maskp,
                                     lq1, lk1, lq2, lk2, lnw, lnb, yb);

  gemm_bt<2, false><<<dim3(8, 32), 256, 0, stream>>>(yb, WcT, bc, d_out, 4096, 1024, 2048);
}

// Round 18
// 319.577 us; speedup vs baseline: 1.3538x; 1.0175x over previous
//
#include <hip/hip_runtime.h>
#include <hip/hip_bf16.h>
#include <stdint.h>

// MultiHeadDiffAttention — R18 = R17 (proven 325us anchor) + two HOST-side
// consolidations measured safe in R16's decomposition (non-diffattn 143->126us):
// cvt3_bf16 (q|k|v one launch into contiguous qb|kb|vb) and bias2_concat.
// diffattn & gemm_bt sources are byte-identical to R17 — loop body is at a
// hipcc regalloc knife-edge (R15/R16 spills); do not perturb.
// B=2, T=2048, C=1024, H=16, HS=64.

#define T_SEQ 2048

typedef unsigned short u16;
typedef __attribute__((ext_vector_type(8))) short short8;
typedef __attribute__((ext_vector_type(4))) float f32x4;
typedef __attribute__((ext_vector_type(16))) float f32x16;

#define LAMBDA_INIT 0.35550906759096926f
#define ONE_MINUS_LI 0.6444909324090307f
#define SM_SCALE 0.125f
#define LOG2E 1.44269504f

__device__ __forceinline__ u16 f2bf(float f) {
  uint32_t u = __float_as_uint(f);
  return (u16)((u + 0x7FFFu + ((u >> 16) & 1u)) >> 16);
}
__device__ __forceinline__ float b2f(u16 u) {
  return __uint_as_float(((uint32_t)u) << 16);
}
__device__ __forceinline__ short8 ld8(const u16* p) {
  return *reinterpret_cast<const short8*>(p);
}
__device__ __forceinline__ void st8(u16* p, short8 v) {
  *reinterpret_cast<short8*>(p) = v;
}
__device__ __forceinline__ f32x4 mfma16(short8 a, short8 b, f32x4 c) {
  return __builtin_amdgcn_mfma_f32_16x16x32_bf16(a, b, c, 0, 0, 0);
}
__device__ __forceinline__ f32x16 mfma32(short8 a, short8 b, f32x16 c) {
  return __builtin_amdgcn_mfma_f32_32x32x16_bf16(a, b, c, 0, 0, 0);
}
__device__ __forceinline__ uint32_t cvtpk(float lo, float hi_) {
  uint32_t r;
  asm("v_cvt_pk_bf16_f32 %0, %1, %2" : "=v"(r) : "v"(lo), "v"(hi_));
  return r;
}

// ------------- merged elementwise f32 -> bf16 (q,k,v in one launch) -------------
__global__ __launch_bounds__(256) void cvt3_bf16(const float* __restrict__ q,
                                                 const float* __restrict__ k,
                                                 const float* __restrict__ v,
                                                 u16* __restrict__ out, int n) {
  int i = (blockIdx.x * 256 + threadIdx.x) * 4;  // over 3n elems
  const float* src;
  int j = i;
  if (i < n) src = q;
  else if (i < 2 * n) { src = k; j = i - n; }
  else { src = v; j = i - 2 * n; }
  float4 f = *reinterpret_cast<const float4*>(src + j);
  union { u16 u[4]; uint2 v2; } pk;
  pk.u[0] = f2bf(f.x); pk.u[1] = f2bf(f.y); pk.u[2] = f2bf(f.z); pk.u[3] = f2bf(f.w);
  *reinterpret_cast<uint2*>(out + i) = pk.v2;
}

// ------------- transpose + convert: W[K][N] f32 -> WT[N][K] bf16 -------------
__global__ __launch_bounds__(256) void tcvt(const float* __restrict__ W,
                                            u16* __restrict__ WT,
                                            int K, int N, int outRowOff) {
  __shared__ float tile[32][33];
  int n0 = blockIdx.x * 32, k0 = blockIdx.y * 32;
  int tx = threadIdx.x & 31, ty = threadIdx.x >> 5;  // ty 0..7
#pragma unroll
  for (int p = 0; p < 4; ++p)
    tile[ty + 8 * p][tx] = W[(size_t)(k0 + ty + 8 * p) * N + n0 + tx];
  __syncthreads();
#pragma unroll
  for (int p = 0; p < 4; ++p)
    WT[(size_t)(outRowOff + n0 + ty + 8 * p) * K + k0 + tx] = f2bf(tile[tx][ty + 8 * p]);
}

// ---------------- concat four 1024-float biases (biasq|biask contiguous) ------
__global__ __launch_bounds__(256) void bias2_concat(const float* __restrict__ bq1,
                                                    const float* __restrict__ bq2,
                                                    const float* __restrict__ bk1,
                                                    const float* __restrict__ bk2,
                                                    float* __restrict__ out) {
  int i = blockIdx.x * 256 + threadIdx.x;  // 0..4095
  const float* src;
  int j;
  if (i < 1024) { src = bq1; j = i; }
  else if (i < 2048) { src = bq2; j = i - 1024; }
  else if (i < 3072) { src = bk1; j = i - 2048; }
  else { src = bk2; j = i - 3072; }
  out[i] = src[j];
}

// ---------------- GEMM: C[M][N] = A[M][K] @ BT[N][K]^T + bias ----------------
// m97 geometry: 128x128 tile, BK=64, 4 waves, global_load_lds width 16.
// EPI 1: bf16 vvT ((b*2048+col)*2048 + t).  EPI 2: f32 [M][N].
// EPI 4 (fused q|k): rows<4096 -> bf16 [M][2048] q1q2; rows>=4096 -> kT layout
//   kT[((b*2+stream)*16+h)][t][d] at Cv+8388608 (stream=col>>10, h=(col>>6)&15).
#define BM 128
#define BN 128
#define BK 64

template <int EPI, bool QK>
__global__ __launch_bounds__(256) void gemm_bt(const u16* __restrict__ A,
                                               const u16* __restrict__ BT,
                                               const float* __restrict__ bias,
                                               void* __restrict__ Cv,
                                               int M, int N, int K) {
  __shared__ __align__(16) u16 As[BM * BK];
  __shared__ __align__(16) u16 Bs[BN * BK];
  int t = threadIdx.x;
  int w = t >> 6, l = t & 63;
  int g = l >> 4, c16 = l & 15;
  int wr = w >> 1, wc = w & 1;
  size_t gm = (size_t)blockIdx.y * BM, gn = (size_t)blockIdx.x * BN;
  if (QK && gm >= 4096) {
    BT += (size_t)2048 * 1024;  // Wk12T follows Wq12T
    bias += 2048;               // biask follows biasq
  }

  f32x4 acc[4][4] = {};

  int srow = l >> 3;       // 0..7 (8 lanes per row, 8 elems each)
  int scol = (l & 7) * 8;  // 0..56
  const u16* Ag = A + (gm + w * 32 + srow) * (size_t)K + scol;
  const u16* Bg = BT + (gn + w * 32 + srow) * (size_t)K + scol;

  for (int kt = 0; kt < K; kt += BK) {
    __syncthreads();
#pragma unroll
    for (int c = 0; c < 4; ++c) {
      __builtin_amdgcn_global_load_lds(
          (const __attribute__((address_space(1))) void*)(Ag + (size_t)(c * 8) * K + kt),
          (__attribute__((address_space(3))) void*)&As[(w * 32 + c * 8) * BK], 16, 0, 0);
      __builtin_amdgcn_global_load_lds(
          (const __attribute__((address_space(1))) void*)(Bg + (size_t)(c * 8) * K + kt),
          (__attribute__((address_space(3))) void*)&Bs[(w * 32 + c * 8) * BK], 16, 0, 0);
    }
    __syncthreads();
#pragma unroll
    for (int kk = 0; kk < 2; ++kk) {
      short8 af[4], bf[4];
#pragma unroll
      for (int m = 0; m < 4; ++m)
        af[m] = *reinterpret_cast<const short8*>(
            &As[(wr * 64 + m * 16 + c16) * BK + kk * 32 + g * 8]);
#pragma unroll
      for (int n = 0; n < 4; ++n)
        bf[n] = *reinterpret_cast<const short8*>(
            &Bs[(wc * 64 + n * 16 + c16) * BK + kk * 32 + g * 8]);
#pragma unroll
      for (int m = 0; m < 4; ++m)
#pragma unroll
        for (int n = 0; n < 4; ++n)
          acc[m][n] = mfma16(af[m], bf[n], acc[m][n]);
    }
  }

#pragma unroll
  for (int m = 0; m < 4; ++m)
#pragma unroll
    for (int n = 0; n < 4; ++n) {
      int row0 = (int)gm + wr * 64 + m * 16 + g * 4;
      int col = (int)gn + wc * 64 + n * 16 + c16;
      float bz = bias[col];
      if (EPI == 1) {
        u16* C = (u16*)Cv;
        int bb = row0 >> 11, tt = row0 & 2047;
        union { u16 u[4]; uint2 v; } pk;
#pragma unroll
        for (int r = 0; r < 4; ++r) pk.u[r] = f2bf(acc[m][n][r] + bz);
        *reinterpret_cast<uint2*>(&C[((size_t)(bb * 2048 + col)) * 2048 + tt]) = pk.v;
      } else if (EPI == 2) {
        float* C = (float*)Cv;
#pragma unroll
        for (int r = 0; r < 4; ++r)
          C[(size_t)(row0 + r) * N + col] = acc[m][n][r] + bz;
      } else {  // EPI == 4: fused q|k
        u16* C = (u16*)Cv;
        if (row0 < 4096) {
#pragma unroll
          for (int r = 0; r < 4; ++r)
            C[(size_t)(row0 + r) * N + col] = f2bf(acc[m][n][r] + bz);
        } else {
          int t0 = row0 - 4096;
          int bb = t0 >> 11, tt = t0 & 2047;
          int str = col >> 10, hh = (col >> 6) & 15, dd = col & 63;
          u16* KT = C + 8388608;
          size_t base = (((size_t)(bb * 2 + str) * 16 + hh) * 2048 + tt) * (size_t)64 + dd;
#pragma unroll
          for (int r = 0; r < 4; ++r) KT[base + (size_t)r * 64] = f2bf(acc[m][n][r] + bz);
        }
      }
    }
}

// ---------------- differential flash attention + fused LN (32x32 swapped) ----
// grid 1024 (1D, XCD-swizzled), block 256 = 4 waves = 2 pairs.
// Pair p covers q-rows [xblk*64 + p*32, +32); wave stream s handles stream s+1.
// 64-key staged tiles, 2-barrier R8/R12-proven staging, COALESCED sources:
// K from kT (contiguous 8KB/stream/tile), V along t (64B/thread contiguous).
#define KROW 72   // K/V LDS row: 64 elems + 8 pad (144B)
#define YROW 72
__global__ __launch_bounds__(256, 3) void diffattn(
    const u16* __restrict__ q1q2, const u16* __restrict__ kT,
    const u16* __restrict__ vvT, const int* __restrict__ mask,
    const float* __restrict__ lq1, const float* __restrict__ lk1,
    const float* __restrict__ lq2, const float* __restrict__ lk2,
    const float* __restrict__ lnw, const float* __restrict__ lnb,
    u16* __restrict__ yout) {
  // Ks [128 rows = stream*64+key][KROW] = 9216 ; Vs [128 d-rows][KROW] = 9216
  __shared__ __align__(16) u16 smem[18432];
  u16* Ksm = smem;
  u16* Vsm = smem + 9216;
  u16* Ysm = smem;  // epilogue overlay

  int tid = threadIdx.x;
  int w = tid >> 6, l = tid & 63;
  int q = l & 31, hi = l >> 5;
  int pair = w >> 1, stream = w & 1;

  // XCD swizzle: same-(b,h) q-blocks land on one XCD -> K/V L2-local
  int id = blockIdx.x;            // 0..1023
  int j = id & 7, rest = id >> 3;
  int xblk = rest & 31, ygrp = rest >> 5;
  int bh = ygrp * 8 + j;
  int b = bh >> 4, h = bh & 15;
  int qr0 = xblk * 64 + pair * 32;

  // lambda
  float lm1 = lq1[h * 64 + l] * lk1[h * 64 + l];
  float lm2 = lq2[h * 64 + l] * lk2[h * 64 + l];
#pragma unroll
  for (int o = 32; o; o >>= 1) {
    lm1 += __shfl_xor(lm1, o);
    lm2 += __shfl_xor(lm2, o);
  }
  float lam = __expf(lm1) - __expf(lm2) + LAMBDA_INIT;

  int soff = stream * 1024;
  const u16* qrow = q1q2 + (size_t)(b * T_SEQ + qr0 + q) * 2048 + h * 64 + soff + hi * 8;
  short8 qf[4];
#pragma unroll
  for (int c = 0; c < 4; ++c) qf[c] = ld8(qrow + c * 16);

  // softmax in log2 domain; mask folds into scale (0 -> uniform softmax)
  float scale = (mask[b * T_SEQ + qr0 + q] == 0) ? 0.f : (SM_SCALE * LOG2E);

  float M = -INFINITY, Lp = 0.f;
  f32x16 acc[4] = {};

  // ---- coalesced staging (256 threads, 8 ld8/thread, all contiguous) ----
  // K: per stream, thread t covers 16 contiguous elems at offset t*16 of the
  //    64x64 kT tile (8KB contiguous per tile).
  int koff = tid * 16;                 // 0..4095
  int krw = koff >> 6, kcl = koff & 63;
  const u16* srcK0 = kT + (((size_t)(b * 2 + 0) * 16 + h) * 2048) * 64 + koff;
  const u16* srcK1 = kT + (((size_t)(b * 2 + 1) * 16 + h) * 2048) * 64 + koff;
  u16* dstK0 = &Ksm[krw * KROW + kcl];
  u16* dstK1 = &Ksm[(64 + krw) * KROW + kcl];
  // V: thread t covers 32 contiguous t-elems of d-row (t>>1) at col (t&1)*32.
  int vd0 = tid >> 1, tcol = (tid & 1) * 32;
  const u16* srcV = vvT + ((size_t)(b * 16 + h) * 128 + vd0) * 2048 + tcol;
  u16* dstV = &Vsm[vd0 * KROW + tcol];

  short8 kpa0, kpa1, kpb0, kpb1, vp0, vp1, vp2, vp3;
  kpa0 = ld8(srcK0); kpa1 = ld8(srcK0 + 8);
  kpb0 = ld8(srcK1); kpb1 = ld8(srcK1 + 8);
  vp0 = ld8(srcV); vp1 = ld8(srcV + 8); vp2 = ld8(srcV + 16); vp3 = ld8(srcV + 24);

  for (int kt = 0; kt < T_SEQ; kt += 64) {
    __syncthreads();  // previous tile's reads complete
    st8(dstK0, kpa0); st8(dstK0 + 8, kpa1);
    st8(dstK1, kpb0); st8(dstK1 + 8, kpb1);
    st8(dstV, vp0); st8(dstV + 8, vp1); st8(dstV + 16, vp2); st8(dstV + 24, vp3);
    __syncthreads();  // tile staged
    if (kt + 64 < T_SEQ) {  // prefetch next tile (consumed NEXT iter)
      size_t ko = (size_t)(kt + 64) * 64;
      kpa0 = ld8(srcK0 + ko); kpa1 = ld8(srcK0 + ko + 8);
      kpb0 = ld8(srcK1 + ko); kpb1 = ld8(srcK1 + ko + 8);
      const u16* nv = srcV + kt + 64;
      vp0 = ld8(nv); vp1 = ld8(nv + 8); vp2 = ld8(nv + 16); vp3 = ld8(nv + 24);
    }

#pragma unroll
    for (int st = 0; st < 2; ++st) {
      const u16* kbase = &Ksm[(stream * 64 + st * 32 + q) * KROW + hi * 8];
      short8 kf[4];
#pragma unroll
      for (int c = 0; c < 4; ++c) kf[c] = ld8(kbase + c * 16);

      f32x16 s = {};
#pragma unroll
      for (int c = 0; c < 4; ++c) s = mfma32(kf[c], qf[c], s);

      // tile max: max3-fusable tree + cross-half
      float m0 = fmaxf(fmaxf(s[0], s[1]), s[2]);
      float m1 = fmaxf(fmaxf(s[3], s[4]), s[5]);
      float m2 = fmaxf(fmaxf(s[6], s[7]), s[8]);
      float m3 = fmaxf(fmaxf(s[9], s[10]), s[11]);
      float m4 = fmaxf(fmaxf(s[12], s[13]), s[14]);
      float ma = fmaxf(fmaxf(m0, m1), m2);
      float mb = fmaxf(fmaxf(m3, m4), s[15]);
      float rm = fmaxf(ma, mb);
      rm = fmaxf(rm, __shfl_xor(rm, 32));
      float tm = rm * scale;

      // defer-max (log2 units: 11.5 ~ e^8); M synced across halves
      if (!__all(tm - M <= 11.5f)) {
        float Mn = fmaxf(M, tm);
        float a = exp2f(M - Mn);
        Lp *= a;
#pragma unroll
        for (int d = 0; d < 4; ++d) acc[d] *= a;
        M = Mn;
      }

      // p = exp2(s*scale - M); lane-local partial sum (combined once at end)
      float p[16];
#pragma unroll
      for (int r = 0; r < 16; ++r) p[r] = exp2f(__builtin_fmaf(s[r], scale, -M));
      float s8[8], s4[4];
#pragma unroll
      for (int i = 0; i < 8; ++i) s8[i] = p[i] + p[i + 8];
#pragma unroll
      for (int i = 0; i < 4; ++i) s4[i] = s8[i] + s8[i + 4];
      Lp += (s4[0] + s4[1]) + (s4[2] + s4[3]);

      // P^T B-frags in-register
      uint32_t a1 = cvtpk(p[0], p[1]), a2 = cvtpk(p[2], p[3]);
      uint32_t b1 = cvtpk(p[4], p[5]), b2 = cvtpk(p[6], p[7]);
      uint32_t c1 = cvtpk(p[8], p[9]), c2 = cvtpk(p[10], p[11]);
      uint32_t d1 = cvtpk(p[12], p[13]), d2 = cvtpk(p[14], p[15]);
      uint32_t sa1 = (uint32_t)__shfl_xor((int)a1, 32), sa2 = (uint32_t)__shfl_xor((int)a2, 32);
      uint32_t sb1 = (uint32_t)__shfl_xor((int)b1, 32), sb2 = (uint32_t)__shfl_xor((int)b2, 32);
      uint32_t sc1 = (uint32_t)__shfl_xor((int)c1, 32), sc2 = (uint32_t)__shfl_xor((int)c2, 32);
      uint32_t sd1 = (uint32_t)__shfl_xor((int)d1, 32), sd2 = (uint32_t)__shfl_xor((int)d2, 32);
      union { uint32_t u[4]; short8 s8v; } pu0, pu1;
      pu0.u[0] = hi ? sb1 : a1;  pu0.u[1] = hi ? sb2 : a2;
      pu0.u[2] = hi ? b1 : sa1;  pu0.u[3] = hi ? b2 : sa2;
      pu1.u[0] = hi ? sd1 : c1;  pu1.u[1] = hi ? sd2 : c2;
      pu1.u[2] = hi ? d1 : sc1;  pu1.u[3] = hi ? d2 : sc2;
      short8 pf0 = pu0.s8v, pf1 = pu1.s8v;

#pragma unroll
      for (int d = 0; d < 4; ++d) {
        const u16* vb0 = &Vsm[(d * 32 + q) * KROW + st * 32 + hi * 8];
        short8 vf0 = ld8(vb0);
        short8 vf1 = ld8(vb0 + 16);
        acc[d] = mfma32(vf0, pf0, acc[d]);
        acc[d] = mfma32(vf1, pf1, acc[d]);
      }
    }
  }

  float L = Lp + __shfl_xor(Lp, 32);
  float inv = 1.f / L;
  __syncthreads();  // staging dead -> Ysm overlay safe
  if (stream == 1) {
    u16* yrow = &Ysm[(pair * 64 + l) * YROW];
#pragma unroll
    for (int d = 0; d < 4; ++d) {
      union { uint32_t u[8]; short8 v[2]; } pk;
#pragma unroll
      for (int i = 0; i < 8; ++i)
        pk.u[i] = cvtpk(acc[d][2 * i] * inv, acc[d][2 * i + 1] * inv);
      st8(yrow + d * 16, pk.v[0]);
      st8(yrow + d * 16 + 8, pk.v[1]);
    }
  }
  __syncthreads();
  if (stream == 0) {
    const u16* yrow = &Ysm[(pair * 64 + l) * YROW];
    float y[4][16];
#pragma unroll
    for (int d = 0; d < 4; ++d) {
      short8 y2a = ld8(yrow + d * 16);
      short8 y2b = ld8(yrow + d * 16 + 8);
#pragma unroll
      for (int i = 0; i < 8; ++i) {
        y[d][i] = acc[d][i] * inv - lam * b2f((u16)y2a[i]);
        y[d][8 + i] = acc[d][8 + i] * inv - lam * b2f((u16)y2b[i]);
      }
    }
    float sm = 0.f;
#pragma unroll
    for (int d = 0; d < 4; ++d)
#pragma unroll
      for (int r = 0; r < 16; ++r) sm += y[d][r];
    sm += __shfl_xor(sm, 32);
    float u = sm * (1.f / 128.f);
    float var = 0.f;
#pragma unroll
    for (int d = 0; d < 4; ++d)
#pragma unroll
      for (int r = 0; r < 16; ++r) { float dd = y[d][r] - u; var += dd * dd; }
    var += __shfl_xor(var, 32);
    float rstd = rsqrtf(var * (1.f / 128.f) + 1e-12f);

    size_t orow = (size_t)(b * T_SEQ + qr0 + q) * 2048 + h * 128;
#pragma unroll
    for (int d = 0; d < 4; ++d)
#pragma unroll
      for (int rr = 0; rr < 4; ++rr) {
        int base = d * 32 + 8 * rr + 4 * hi;
        union { u16 u[4]; uint2 v; } o;
#pragma unroll
        for (int i = 0; i < 4; ++i) {
          float yv = (lnw[base + i] * ((y[d][rr * 4 + i] - u) * rstd) + lnb[base + i]) *
                     ONE_MINUS_LI;
          o.u[i] = f2bf(yv);
        }
        *reinterpret_cast<uint2*>(&yout[orow + base]) = o.v;
      }
  }
}

// ---------------- host ----------------
extern "C" void kernel_launch(void* const* d_in, const int* in_sizes, int n_in,
                              void* d_out, int out_size, void* d_ws, size_t ws_size,
                              hipStream_t stream) {
  (void)in_sizes; (void)n_in; (void)out_size; (void)ws_size;
  const float* q   = (const float*)d_in[0];
  const float* k   = (const float*)d_in[1];
  const float* v   = (const float*)d_in[2];
  const int* maskp = (const int*)d_in[3];
  const float* Wq1 = (const float*)d_in[4];
  const float* bq1 = (const float*)d_in[5];
  const float* Wq2 = (const float*)d_in[6];
  const float* bq2 = (const float*)d_in[7];
  const float* Wk1 = (const float*)d_in[8];
  const float* bk1 = (const float*)d_in[9];
  const float* Wk2 = (const float*)d_in[10];
  const float* bk2 = (const float*)d_in[11];
  const float* Wv  = (const float*)d_in[12];
  const float* bv  = (const float*)d_in[13];
  const float* Wc  = (const float*)d_in[14];
  const float* bc  = (const float*)d_in[15];
  const float* lnw = (const float*)d_in[16];
  const float* lnb = (const float*)d_in[17];
  const float* lq1 = (const float*)d_in[18];
  const float* lk1 = (const float*)d_in[19];
  const float* lq2 = (const float*)d_in[20];
  const float* lk2 = (const float*)d_in[21];

  char* ws = (char*)d_ws;
  u16* qb     = (u16*)(ws + 0);          // qb|kb|vb contiguous (24MB)
  u16* vb     = (u16*)(ws + 16777216);
  u16* Wq12T  = (u16*)(ws + 25165824);   // Wk12T contiguous after
  u16* WvT    = (u16*)(ws + 33554432);
  u16* WcT    = (u16*)(ws + 37748736);
  float* biasq = (float*)(ws + 41943040);  // biask contiguous after
  u16* q1q2   = (u16*)(ws + 41959424);   // kT contiguous after (+8388608 elems)
  u16* kT     = (u16*)(ws + 58736640);
  u16* vvT    = (u16*)(ws + 75513856);
  u16* yb     = (u16*)(ws + 0);  // alias qb+kb (16MB; both dead before attention)

  const int NELEM = 2 * T_SEQ * 1024;  // 4,194,304

  cvt3_bf16<<<12288, 256, 0, stream>>>(q, k, v, qb, NELEM);

  tcvt<<<dim3(32, 32), 256, 0, stream>>>(Wq1, Wq12T, 1024, 1024, 0);
  tcvt<<<dim3(32, 32), 256, 0, stream>>>(Wq2, Wq12T, 1024, 1024, 1024);
  tcvt<<<dim3(32, 32), 256, 0, stream>>>(Wk1, Wq12T, 1024, 1024, 2048);
  tcvt<<<dim3(32, 32), 256, 0, stream>>>(Wk2, Wq12T, 1024, 1024, 3072);
  tcvt<<<dim3(64, 32), 256, 0, stream>>>(Wv, WvT, 1024, 2048, 0);
  tcvt<<<dim3(32, 64), 256, 0, stream>>>(Wc, WcT, 2048, 1024, 0);

  bias2_concat<<<16, 256, 0, stream>>>(bq1, bq2, bk1, bk2, biasq);

  // fused q-proj + k-proj: M=8192; q-half -> q1q2 (bf16 MN), k-half -> kT layout
  gemm_bt<4, true><<<dim3(16, 64), 256, 0, stream>>>(qb, Wq12T, biasq, q1q2,
                                                     8192, 2048, 1024);
  gemm_bt<1, false><<<dim3(16, 32), 256, 0, stream>>>(vb, WvT, bv, vvT, 4096, 2048, 1024);

  diffattn<<<1024, 256, 0, stream>>>(q1q2, kT, vvT, maskp,
                                     lq1, lk1, lq2, lk2, lnw, lnb, yb);

  gemm_bt<2, false><<<dim3(8, 32), 256, 0, stream>>>(yb, WcT, bc, d_out, 4096, 1024, 2048);
}

// Round 20
// 311.559 us; speedup vs baseline: 1.3886x; 1.0257x over previous
//
#include <hip/hip_runtime.h>
#include <hip/hip_bf16.h>
#include <stdint.h>

// MultiHeadDiffAttention — R20. R19's failure: bias3[6144] (24.6KB) overran its
// 16KB slot and overlapped q1q2's first rows (GEMM read bias while writing
// q1q2 -> corrupt bv). Fix: R18's bias2[4096] (exactly fits) + pass bv (f32
// device input) directly as a second bias pointer for the v-range of the
// merged projection GEMM. All else identical to R19; diffattn byte-identical
// to R17/R18 (regalloc knife-edge — frozen).
// B=2, T=2048, C=1024, H=16, HS=64.

#define T_SEQ 2048

typedef unsigned short u16;
typedef __attribute__((ext_vector_type(8))) short short8;
typedef __attribute__((ext_vector_type(4))) float f32x4;
typedef __attribute__((ext_vector_type(16))) float f32x16;

#define LAMBDA_INIT 0.35550906759096926f
#define ONE_MINUS_LI 0.6444909324090307f
#define SM_SCALE 0.125f
#define LOG2E 1.44269504f

__device__ __forceinline__ u16 f2bf(float f) {
  uint32_t u = __float_as_uint(f);
  return (u16)((u + 0x7FFFu + ((u >> 16) & 1u)) >> 16);
}
__device__ __forceinline__ float b2f(u16 u) {
  return __uint_as_float(((uint32_t)u) << 16);
}
__device__ __forceinline__ short8 ld8(const u16* p) {
  return *reinterpret_cast<const short8*>(p);
}
__device__ __forceinline__ void st8(u16* p, short8 v) {
  *reinterpret_cast<short8*>(p) = v;
}
__device__ __forceinline__ f32x4 mfma16(short8 a, short8 b, f32x4 c) {
  return __builtin_amdgcn_mfma_f32_16x16x32_bf16(a, b, c, 0, 0, 0);
}
__device__ __forceinline__ f32x16 mfma32(short8 a, short8 b, f32x16 c) {
  return __builtin_amdgcn_mfma_f32_32x32x16_bf16(a, b, c, 0, 0, 0);
}
__device__ __forceinline__ uint32_t cvtpk(float lo, float hi_) {
  uint32_t r;
  asm("v_cvt_pk_bf16_f32 %0, %1, %2" : "=v"(r) : "v"(lo), "v"(hi_));
  return r;
}

// ------------- merged elementwise f32 -> bf16 (q,k,v in one launch) -------------
__global__ __launch_bounds__(256) void cvt3_bf16(const float* __restrict__ q,
                                                 const float* __restrict__ k,
                                                 const float* __restrict__ v,
                                                 u16* __restrict__ out, int n) {
  int i = (blockIdx.x * 256 + threadIdx.x) * 4;  // over 3n elems
  const float* src;
  int j = i;
  if (i < n) src = q;
  else if (i < 2 * n) { src = k; j = i - n; }
  else { src = v; j = i - 2 * n; }
  float4 f = *reinterpret_cast<const float4*>(src + j);
  union { u16 u[4]; uint2 v2; } pk;
  pk.u[0] = f2bf(f.x); pk.u[1] = f2bf(f.y); pk.u[2] = f2bf(f.z); pk.u[3] = f2bf(f.w);
  *reinterpret_cast<uint2*>(out + i) = pk.v2;
}

// ------------- transpose + convert: W[K][N] f32 -> WT[N][K] bf16 -------------
__global__ __launch_bounds__(256) void tcvt(const float* __restrict__ W,
                                            u16* __restrict__ WT,
                                            int K, int N, int outRowOff) {
  __shared__ float tile[32][33];
  int n0 = blockIdx.x * 32, k0 = blockIdx.y * 32;
  int tx = threadIdx.x & 31, ty = threadIdx.x >> 5;  // ty 0..7
#pragma unroll
  for (int p = 0; p < 4; ++p)
    tile[ty + 8 * p][tx] = W[(size_t)(k0 + ty + 8 * p) * N + n0 + tx];
  __syncthreads();
#pragma unroll
  for (int p = 0; p < 4; ++p)
    WT[(size_t)(outRowOff + n0 + ty + 8 * p) * K + k0 + tx] = f2bf(tile[tx][ty + 8 * p]);
}

// ----- tcvt4: four 1024x1024 transposes in one launch (z selects source) -----
__global__ __launch_bounds__(256) void tcvt4(const float* __restrict__ W0,
                                             const float* __restrict__ W1,
                                             const float* __restrict__ W2,
                                             const float* __restrict__ W3,
                                             u16* __restrict__ WT) {
  __shared__ float tile[32][33];
  int z = blockIdx.z;
  const float* W = (z == 0) ? W0 : (z == 1) ? W1 : (z == 2) ? W2 : W3;
  int outRowOff = z * 1024;
  int n0 = blockIdx.x * 32, k0 = blockIdx.y * 32;
  int tx = threadIdx.x & 31, ty = threadIdx.x >> 5;
#pragma unroll
  for (int p = 0; p < 4; ++p)
    tile[ty + 8 * p][tx] = W[(size_t)(k0 + ty + 8 * p) * 1024 + n0 + tx];
  __syncthreads();
#pragma unroll
  for (int p = 0; p < 4; ++p)
    WT[(size_t)(outRowOff + n0 + ty + 8 * p) * 1024 + k0 + tx] = f2bf(tile[tx][ty + 8 * p]);
}

// ---------------- concat four 1024-float biases (biasq|biask contiguous) ------
__global__ __launch_bounds__(256) void bias2_concat(const float* __restrict__ bq1,
                                                    const float* __restrict__ bq2,
                                                    const float* __restrict__ bk1,
                                                    const float* __restrict__ bk2,
                                                    float* __restrict__ out) {
  int i = blockIdx.x * 256 + threadIdx.x;  // 0..4095
  const float* src;
  int j;
  if (i < 1024) { src = bq1; j = i; }
  else if (i < 2048) { src = bq2; j = i - 1024; }
  else if (i < 3072) { src = bk1; j = i - 2048; }
  else { src = bk2; j = i - 3072; }
  out[i] = src[j];
}

// ---------------- GEMM: C[M][N] = A[M][K] @ BT[N][K]^T + bias ----------------
// m97 geometry: 128x128 tile, BK=64, 4 waves, global_load_lds width 16.
// EPI 2: f32 [M][N].
// EPI 5 (fused q|k|v, N=2048): rows<4096 -> bf16 q1q2[M][2048];
//   rows 4096..8191 -> kT[((b*2+stream)*16+h)][t][d] at Cv+8388608;
//   rows >=8192 -> vvT ((b*2048+col)*2048+t) at Cv+16777216, bias from biasV.
#define BM 128
#define BN 128
#define BK 64

template <int EPI>
__global__ __launch_bounds__(256) void gemm_bt(const u16* __restrict__ A,
                                               const u16* __restrict__ BT,
                                               const float* __restrict__ bias,
                                               const float* __restrict__ biasV,
                                               void* __restrict__ Cv,
                                               int M, int N, int K) {
  __shared__ __align__(16) u16 As[BM * BK];
  __shared__ __align__(16) u16 Bs[BN * BK];
  int t = threadIdx.x;
  int w = t >> 6, l = t & 63;
  int g = l >> 4, c16 = l & 15;
  int wr = w >> 1, wc = w & 1;
  size_t gm = (size_t)blockIdx.y * BM, gn = (size_t)blockIdx.x * BN;
  if (EPI == 5) {
    if (gm >= 8192) {
      BT += (size_t)4096 * 1024;  // WvT after Wk12T
      bias = biasV;               // bv (f32 device input), no offset
    } else if (gm >= 4096) {
      BT += (size_t)2048 * 1024;  // Wk12T after Wq12T
      bias += 2048;               // biask after biasq
    }
  }

  f32x4 acc[4][4] = {};

  int srow = l >> 3;       // 0..7 (8 lanes per row, 8 elems each)
  int scol = (l & 7) * 8;  // 0..56
  const u16* Ag = A + (gm + w * 32 + srow) * (size_t)K + scol;
  const u16* Bg = BT + (gn + w * 32 + srow) * (size_t)K + scol;

  for (int kt = 0; kt < K; kt += BK) {
    __syncthreads();
#pragma unroll
    for (int c = 0; c < 4; ++c) {
      __builtin_amdgcn_global_load_lds(
          (const __attribute__((address_space(1))) void*)(Ag + (size_t)(c * 8) * K + kt),
          (__attribute__((address_space(3))) void*)&As[(w * 32 + c * 8) * BK], 16, 0, 0);
      __builtin_amdgcn_global_load_lds(
          (const __attribute__((address_space(1))) void*)(Bg + (size_t)(c * 8) * K + kt),
          (__attribute__((address_space(3))) void*)&Bs[(w * 32 + c * 8) * BK], 16, 0, 0);
    }
    __syncthreads();
#pragma unroll
    for (int kk = 0; kk < 2; ++kk) {
      short8 af[4], bf[4];
#pragma unroll
      for (int m = 0; m < 4; ++m)
        af[m] = *reinterpret_cast<const short8*>(
            &As[(wr * 64 + m * 16 + c16) * BK + kk * 32 + g * 8]);
#pragma unroll
      for (int n = 0; n < 4; ++n)
        bf[n] = *reinterpret_cast<const short8*>(
            &Bs[(wc * 64 + n * 16 + c16) * BK + kk * 32 + g * 8]);
#pragma unroll
      for (int m = 0; m < 4; ++m)
#pragma unroll
        for (int n = 0; n < 4; ++n)
          acc[m][n] = mfma16(af[m], bf[n], acc[m][n]);
    }
  }

#pragma unroll
  for (int m = 0; m < 4; ++m)
#pragma unroll
    for (int n = 0; n < 4; ++n) {
      int row0 = (int)gm + wr * 64 + m * 16 + g * 4;
      int col = (int)gn + wc * 64 + n * 16 + c16;
      float bz = bias[col];
      if (EPI == 2) {
        float* C = (float*)Cv;
#pragma unroll
        for (int r = 0; r < 4; ++r)
          C[(size_t)(row0 + r) * N + col] = acc[m][n][r] + bz;
      } else {  // EPI == 5: fused q|k|v
        u16* C = (u16*)Cv;
        if (row0 < 4096) {
#pragma unroll
          for (int r = 0; r < 4; ++r)
            C[(size_t)(row0 + r) * N + col] = f2bf(acc[m][n][r] + bz);
        } else if (row0 < 8192) {
          int t0 = row0 - 4096;
          int bb = t0 >> 11, tt = t0 & 2047;
          int str = col >> 10, hh = (col >> 6) & 15, dd = col & 63;
          u16* KT = C + 8388608;
          size_t base = (((size_t)(bb * 2 + str) * 16 + hh) * 2048 + tt) * (size_t)64 + dd;
#pragma unroll
          for (int r = 0; r < 4; ++r) KT[base + (size_t)r * 64] = f2bf(acc[m][n][r] + bz);
        } else {
          int t0 = row0 - 8192;
          int bb = t0 >> 11, tt = t0 & 2047;
          u16* VT = C + 16777216;
          union { u16 u[4]; uint2 v; } pk;
#pragma unroll
          for (int r = 0; r < 4; ++r) pk.u[r] = f2bf(acc[m][n][r] + bz);
          *reinterpret_cast<uint2*>(&VT[((size_t)(bb * 2048 + col)) * 2048 + tt]) = pk.v;
        }
      }
    }
}

// ---------------- differential flash attention + fused LN (32x32 swapped) ----
// grid 1024 (1D, XCD-swizzled), block 256 = 4 waves = 2 pairs.
// Pair p covers q-rows [xblk*64 + p*32, +32); wave stream s handles stream s+1.
// 64-key staged tiles, 2-barrier R8/R12-proven staging, COALESCED sources:
// K from kT (contiguous 8KB/stream/tile), V along t (64B/thread contiguous).
#define KROW 72   // K/V LDS row: 64 elems + 8 pad (144B)
#define YROW 72
__global__ __launch_bounds__(256, 3) void diffattn(
    const u16* __restrict__ q1q2, const u16* __restrict__ kT,
    const u16* __restrict__ vvT, const int* __restrict__ mask,
    const float* __restrict__ lq1, const float* __restrict__ lk1,
    const float* __restrict__ lq2, const float* __restrict__ lk2,
    const float* __restrict__ lnw, const float* __restrict__ lnb,
    u16* __restrict__ yout) {
  // Ks [128 rows = stream*64+key][KROW] = 9216 ; Vs [128 d-rows][KROW] = 9216
  __shared__ __align__(16) u16 smem[18432];
  u16* Ksm = smem;
  u16* Vsm = smem + 9216;
  u16* Ysm = smem;  // epilogue overlay

  int tid = threadIdx.x;
  int w = tid >> 6, l = tid & 63;
  int q = l & 31, hi = l >> 5;
  int pair = w >> 1, stream = w & 1;

  // XCD swizzle: same-(b,h) q-blocks land on one XCD -> K/V L2-local
  int id = blockIdx.x;            // 0..1023
  int j = id & 7, rest = id >> 3;
  int xblk = rest & 31, ygrp = rest >> 5;
  int bh = ygrp * 8 + j;
  int b = bh >> 4, h = bh & 15;
  int qr0 = xblk * 64 + pair * 32;

  // lambda
  float lm1 = lq1[h * 64 + l] * lk1[h * 64 + l];
  float lm2 = lq2[h * 64 + l] * lk2[h * 64 + l];
#pragma unroll
  for (int o = 32; o; o >>= 1) {
    lm1 += __shfl_xor(lm1, o);
    lm2 += __shfl_xor(lm2, o);
  }
  float lam = __expf(lm1) - __expf(lm2) + LAMBDA_INIT;

  int soff = stream * 1024;
  const u16* qrow = q1q2 + (size_t)(b * T_SEQ + qr0 + q) * 2048 + h * 64 + soff + hi * 8;
  short8 qf[4];
#pragma unroll
  for (int c = 0; c < 4; ++c) qf[c] = ld8(qrow + c * 16);

  // softmax in log2 domain; mask folds into scale (0 -> uniform softmax)
  float scale = (mask[b * T_SEQ + qr0 + q] == 0) ? 0.f : (SM_SCALE * LOG2E);

  float M = -INFINITY, Lp = 0.f;
  f32x16 acc[4] = {};

  // ---- coalesced staging (256 threads, 8 ld8/thread, all contiguous) ----
  // K: per stream, thread t covers 16 contiguous elems at offset t*16 of the
  //    64x64 kT tile (8KB contiguous per tile).
  int koff = tid * 16;                 // 0..4095
  int krw = koff >> 6, kcl = koff & 63;
  const u16* srcK0 = kT + (((size_t)(b * 2 + 0) * 16 + h) * 2048) * 64 + koff;
  const u16* srcK1 = kT + (((size_t)(b * 2 + 1) * 16 + h) * 2048) * 64 + koff;
  u16* dstK0 = &Ksm[krw * KROW + kcl];
  u16* dstK1 = &Ksm[(64 + krw) * KROW + kcl];
  // V: thread t covers 32 contiguous t-elems of d-row (t>>1) at col (t&1)*32.
  int vd0 = tid >> 1, tcol = (tid & 1) * 32;
  const u16* srcV = vvT + ((size_t)(b * 16 + h) * 128 + vd0) * 2048 + tcol;
  u16* dstV = &Vsm[vd0 * KROW + tcol];

  short8 kpa0, kpa1, kpb0, kpb1, vp0, vp1, vp2, vp3;
  kpa0 = ld8(srcK0); kpa1 = ld8(srcK0 + 8);
  kpb0 = ld8(srcK1); kpb1 = ld8(srcK1 + 8);
  vp0 = ld8(srcV); vp1 = ld8(srcV + 8); vp2 = ld8(srcV + 16); vp3 = ld8(srcV + 24);

  for (int kt = 0; kt < T_SEQ; kt += 64) {
    __syncthreads();  // previous tile's reads complete
    st8(dstK0, kpa0); st8(dstK0 + 8, kpa1);
    st8(dstK1, kpb0); st8(dstK1 + 8, kpb1);
    st8(dstV, vp0); st8(dstV + 8, vp1); st8(dstV + 16, vp2); st8(dstV + 24, vp3);
    __syncthreads();  // tile staged
    if (kt + 64 < T_SEQ) {  // prefetch next tile (consumed NEXT iter)
      size_t ko = (size_t)(kt + 64) * 64;
      kpa0 = ld8(srcK0 + ko); kpa1 = ld8(srcK0 + ko + 8);
      kpb0 = ld8(srcK1 + ko); kpb1 = ld8(srcK1 + ko + 8);
      const u16* nv = srcV + kt + 64;
      vp0 = ld8(nv); vp1 = ld8(nv + 8); vp2 = ld8(nv + 16); vp3 = ld8(nv + 24);
    }

#pragma unroll
    for (int st = 0; st < 2; ++st) {
      const u16* kbase = &Ksm[(stream * 64 + st * 32 + q) * KROW + hi * 8];
      short8 kf[4];
#pragma unroll
      for (int c = 0; c < 4; ++c) kf[c] = ld8(kbase + c * 16);

      f32x16 s = {};
#pragma unroll
      for (int c = 0; c < 4; ++c) s = mfma32(kf[c], qf[c], s);

      // tile max: max3-fusable tree + cross-half
      float m0 = fmaxf(fmaxf(s[0], s[1]), s[2]);
      float m1 = fmaxf(fmaxf(s[3], s[4]), s[5]);
      float m2 = fmaxf(fmaxf(s[6], s[7]), s[8]);
      float m3 = fmaxf(fmaxf(s[9], s[10]), s[11]);
      float m4 = fmaxf(fmaxf(s[12], s[13]), s[14]);
      float ma = fmaxf(fmaxf(m0, m1), m2);
      float mb = fmaxf(fmaxf(m3, m4), s[15]);
      float rm = fmaxf(ma, mb);
      rm = fmaxf(rm, __shfl_xor(rm, 32));
      float tm = rm * scale;

      // defer-max (log2 units: 11.5 ~ e^8); M synced across halves
      if (!__all(tm - M <= 11.5f)) {
        float Mn = fmaxf(M, tm);
        float a = exp2f(M - Mn);
        Lp *= a;
#pragma unroll
        for (int d = 0; d < 4; ++d) acc[d] *= a;
        M = Mn;
      }

      // p = exp2(s*scale - M); lane-local partial sum (combined once at end)
      float p[16];
#pragma unroll
      for (int r = 0; r < 16; ++r) p[r] = exp2f(__builtin_fmaf(s[r], scale, -M));
      float s8[8], s4[4];
#pragma unroll
      for (int i = 0; i < 8; ++i) s8[i] = p[i] + p[i + 8];
#pragma unroll
      for (int i = 0; i < 4; ++i) s4[i] = s8[i] + s8[i + 4];
      Lp += (s4[0] + s4[1]) + (s4[2] + s4[3]);

      // P^T B-frags in-register
      uint32_t a1 = cvtpk(p[0], p[1]), a2 = cvtpk(p[2], p[3]);
      uint32_t b1 = cvtpk(p[4], p[5]), b2 = cvtpk(p[6], p[7]);
      uint32_t c1 = cvtpk(p[8], p[9]), c2 = cvtpk(p[10], p[11]);
      uint32_t d1 = cvtpk(p[12], p[13]), d2 = cvtpk(p[14], p[15]);
      uint32_t sa1 = (uint32_t)__shfl_xor((int)a1, 32), sa2 = (uint32_t)__shfl_xor((int)a2, 32);
      uint32_t sb1 = (uint32_t)__shfl_xor((int)b1, 32), sb2 = (uint32_t)__shfl_xor((int)b2, 32);
      uint32_t sc1 = (uint32_t)__shfl_xor((int)c1, 32), sc2 = (uint32_t)__shfl_xor((int)c2, 32);
      uint32_t sd1 = (uint32_t)__shfl_xor((int)d1, 32), sd2 = (uint32_t)__shfl_xor((int)d2, 32);
      union { uint32_t u[4]; short8 s8v; } pu0, pu1;
      pu0.u[0] = hi ? sb1 : a1;  pu0.u[1] = hi ? sb2 : a2;
      pu0.u[2] = hi ? b1 : sa1;  pu0.u[3] = hi ? b2 : sa2;
      pu1.u[0] = hi ? sd1 : c1;  pu1.u[1] = hi ? sd2 : c2;
      pu1.u[2] = hi ? d1 : sc1;  pu1.u[3] = hi ? d2 : sc2;
      short8 pf0 = pu0.s8v, pf1 = pu1.s8v;

#pragma unroll
      for (int d = 0; d < 4; ++d) {
        const u16* vb0 = &Vsm[(d * 32 + q) * KROW + st * 32 + hi * 8];
        short8 vf0 = ld8(vb0);
        short8 vf1 = ld8(vb0 + 16);
        acc[d] = mfma32(vf0, pf0, acc[d]);
        acc[d] = mfma32(vf1, pf1, acc[d]);
      }
    }
  }

  float L = Lp + __shfl_xor(Lp, 32);
  float inv = 1.f / L;
  __syncthreads();  // staging dead -> Ysm overlay safe
  if (stream == 1) {
    u16* yrow = &Ysm[(pair * 64 + l) * YROW];
#pragma unroll
    for (int d = 0; d < 4; ++d) {
      union { uint32_t u[8]; short8 v[2]; } pk;
#pragma unroll
      for (int i = 0; i < 8; ++i)
        pk.u[i] = cvtpk(acc[d][2 * i] * inv, acc[d][2 * i + 1] * inv);
      st8(yrow + d * 16, pk.v[0]);
      st8(yrow + d * 16 + 8, pk.v[1]);
    }
  }
  __syncthreads();
  if (stream == 0) {
    const u16* yrow = &Ysm[(pair * 64 + l) * YROW];
    float y[4][16];
#pragma unroll
    for (int d = 0; d < 4; ++d) {
      short8 y2a = ld8(yrow + d * 16);
      short8 y2b = ld8(yrow + d * 16 + 8);
#pragma unroll
      for (int i = 0; i < 8; ++i) {
        y[d][i] = acc[d][i] * inv - lam * b2f((u16)y2a[i]);
        y[d][8 + i] = acc[d][8 + i] * inv - lam * b2f((u16)y2b[i]);
      }
    }
    float sm = 0.f;
#pragma unroll
    for (int d = 0; d < 4; ++d)
#pragma unroll
      for (int r = 0; r < 16; ++r) sm += y[d][r];
    sm += __shfl_xor(sm, 32);
    float u = sm * (1.f / 128.f);
    float var = 0.f;
#pragma unroll
    for (int d = 0; d < 4; ++d)
#pragma unroll
      for (int r = 0; r < 16; ++r) { float dd = y[d][r] - u; var += dd * dd; }
    var += __shfl_xor(var, 32);
    float rstd = rsqrtf(var * (1.f / 128.f) + 1e-12f);

    size_t orow = (size_t)(b * T_SEQ + qr0 + q) * 2048 + h * 128;
#pragma unroll
    for (int d = 0; d < 4; ++d)
#pragma unroll
      for (int rr = 0; rr < 4; ++rr) {
        int base = d * 32 + 8 * rr + 4 * hi;
        union { u16 u[4]; uint2 v; } o;
#pragma unroll
        for (int i = 0; i < 4; ++i) {
          float yv = (lnw[base + i] * ((y[d][rr * 4 + i] - u) * rstd) + lnb[base + i]) *
                     ONE_MINUS_LI;
          o.u[i] = f2bf(yv);
        }
        *reinterpret_cast<uint2*>(&yout[orow + base]) = o.v;
      }
  }
}

// ---------------- host ----------------
extern "C" void kernel_launch(void* const* d_in, const int* in_sizes, int n_in,
                              void* d_out, int out_size, void* d_ws, size_t ws_size,
                              hipStream_t stream) {
  (void)in_sizes; (void)n_in; (void)out_size; (void)ws_size;
  const float* q   = (const float*)d_in[0];
  const float* k   = (const float*)d_in[1];
  const float* v   = (const float*)d_in[2];
  const int* maskp = (const int*)d_in[3];
  const float* Wq1 = (const float*)d_in[4];
  const float* bq1 = (const float*)d_in[5];
  const float* Wq2 = (const float*)d_in[6];
  const float* bq2 = (const float*)d_in[7];
  const float* Wk1 = (const float*)d_in[8];
  const float* bk1 = (const float*)d_in[9];
  const float* Wk2 = (const float*)d_in[10];
  const float* bk2 = (const float*)d_in[11];
  const float* Wv  = (const float*)d_in[12];
  const float* bv  = (const float*)d_in[13];
  const float* Wc  = (const float*)d_in[14];
  const float* bc  = (const float*)d_in[15];
  const float* lnw = (const float*)d_in[16];
  const float* lnb = (const float*)d_in[17];
  const float* lq1 = (const float*)d_in[18];
  const float* lk1 = (const float*)d_in[19];
  const float* lq2 = (const float*)d_in[20];
  const float* lk2 = (const float*)d_in[21];

  char* ws = (char*)d_ws;
  u16* qb     = (u16*)(ws + 0);          // qb|kb|vb contiguous [12288][1024]
  u16* Wq12T  = (u16*)(ws + 25165824);   // Wq12T|Wk12T|WvT contiguous [6144][1024]
  u16* WvT    = (u16*)(ws + 33554432);
  u16* WcT    = (u16*)(ws + 37748736);
  float* biasq = (float*)(ws + 41943040);  // [4096]: biasq|biask (exactly fits)
  u16* q1q2   = (u16*)(ws + 41959424);   // q1q2|kT|vvT contiguous
  u16* kT     = (u16*)(ws + 58736640);
  u16* vvT    = (u16*)(ws + 75513856);
  u16* yb     = (u16*)(ws + 0);  // alias qb+kb (16MB; both dead before attention)

  const int NELEM = 2 * T_SEQ * 1024;  // 4,194,304

  cvt3_bf16<<<12288, 256, 0, stream>>>(q, k, v, qb, NELEM);

  tcvt4<<<dim3(32, 32, 4), 256, 0, stream>>>(Wq1, Wq2, Wk1, Wk2, Wq12T);
  tcvt<<<dim3(64, 32), 256, 0, stream>>>(Wv, WvT, 1024, 2048, 0);
  tcvt<<<dim3(32, 64), 256, 0, stream>>>(Wc, WcT, 2048, 1024, 0);

  bias2_concat<<<16, 256, 0, stream>>>(bq1, bq2, bk1, bk2, biasq);

  // ONE projection GEMM: M=12288 over qb|kb|vb; epilogues q1q2 / kT / vvT
  gemm_bt<5><<<dim3(16, 96), 256, 0, stream>>>(qb, Wq12T, biasq, bv, q1q2,
                                               12288, 2048, 1024);

  diffattn<<<1024, 256, 0, stream>>>(q1q2, kT, vvT, maskp,
                                     lq1, lk1, lq2, lk2, lnw, lnb, yb);

  gemm_bt<2><<<dim3(8, 32), 256, 0, stream>>>(yb, WcT, bc, bc, d_out, 4096, 1024, 2048);
}

// Round 21
// 303.558 us; speedup vs baseline: 1.4252x; 1.0264x over previous
//
#include <hip/hip_runtime.h>
#include <hip/hip_bf16.h>
#include <stdint.h>

// MultiHeadDiffAttention — R21 = R20 (311.6us) + final-GEMM grid fix:
// the 8x32=256-block final GEMM was 1 block/CU (no latency hiding). New
// gemm_fin: 128x64 tile, 16x32=512 blocks = 2/CU. Also Wv/Wc transposes
// merged into one z-indexed launch. diffattn + projection GEMM byte-identical
// to R20 (diffattn is regalloc-knife-edge frozen).
// B=2, T=2048, C=1024, H=16, HS=64.

#define T_SEQ 2048

typedef unsigned short u16;
typedef __attribute__((ext_vector_type(8))) short short8;
typedef __attribute__((ext_vector_type(4))) float f32x4;
typedef __attribute__((ext_vector_type(16))) float f32x16;

#define LAMBDA_INIT 0.35550906759096926f
#define ONE_MINUS_LI 0.6444909324090307f
#define SM_SCALE 0.125f
#define LOG2E 1.44269504f

__device__ __forceinline__ u16 f2bf(float f) {
  uint32_t u = __float_as_uint(f);
  return (u16)((u + 0x7FFFu + ((u >> 16) & 1u)) >> 16);
}
__device__ __forceinline__ float b2f(u16 u) {
  return __uint_as_float(((uint32_t)u) << 16);
}
__device__ __forceinline__ short8 ld8(const u16* p) {
  return *reinterpret_cast<const short8*>(p);
}
__device__ __forceinline__ void st8(u16* p, short8 v) {
  *reinterpret_cast<short8*>(p) = v;
}
__device__ __forceinline__ f32x4 mfma16(short8 a, short8 b, f32x4 c) {
  return __builtin_amdgcn_mfma_f32_16x16x32_bf16(a, b, c, 0, 0, 0);
}
__device__ __forceinline__ f32x16 mfma32(short8 a, short8 b, f32x16 c) {
  return __builtin_amdgcn_mfma_f32_32x32x16_bf16(a, b, c, 0, 0, 0);
}
__device__ __forceinline__ uint32_t cvtpk(float lo, float hi_) {
  uint32_t r;
  asm("v_cvt_pk_bf16_f32 %0, %1, %2" : "=v"(r) : "v"(lo), "v"(hi_));
  return r;
}

// ------------- merged elementwise f32 -> bf16 (q,k,v in one launch) -------------
__global__ __launch_bounds__(256) void cvt3_bf16(const float* __restrict__ q,
                                                 const float* __restrict__ k,
                                                 const float* __restrict__ v,
                                                 u16* __restrict__ out, int n) {
  int i = (blockIdx.x * 256 + threadIdx.x) * 4;  // over 3n elems
  const float* src;
  int j = i;
  if (i < n) src = q;
  else if (i < 2 * n) { src = k; j = i - n; }
  else { src = v; j = i - 2 * n; }
  float4 f = *reinterpret_cast<const float4*>(src + j);
  union { u16 u[4]; uint2 v2; } pk;
  pk.u[0] = f2bf(f.x); pk.u[1] = f2bf(f.y); pk.u[2] = f2bf(f.z); pk.u[3] = f2bf(f.w);
  *reinterpret_cast<uint2*>(out + i) = pk.v2;
}

// ----- tcvt4: four 1024x1024 transposes in one launch (z selects source) -----
__global__ __launch_bounds__(256) void tcvt4(const float* __restrict__ W0,
                                             const float* __restrict__ W1,
                                             const float* __restrict__ W2,
                                             const float* __restrict__ W3,
                                             u16* __restrict__ WT) {
  __shared__ float tile[32][33];
  int z = blockIdx.z;
  const float* W = (z == 0) ? W0 : (z == 1) ? W1 : (z == 2) ? W2 : W3;
  int outRowOff = z * 1024;
  int n0 = blockIdx.x * 32, k0 = blockIdx.y * 32;
  int tx = threadIdx.x & 31, ty = threadIdx.x >> 5;
#pragma unroll
  for (int p = 0; p < 4; ++p)
    tile[ty + 8 * p][tx] = W[(size_t)(k0 + ty + 8 * p) * 1024 + n0 + tx];
  __syncthreads();
#pragma unroll
  for (int p = 0; p < 4; ++p)
    WT[(size_t)(outRowOff + n0 + ty + 8 * p) * 1024 + k0 + tx] = f2bf(tile[tx][ty + 8 * p]);
}

// ----- tcvt2: Wv (1024x2048) and Wc (2048x1024) in one launch (z selects) -----
__global__ __launch_bounds__(256) void tcvt2(const float* __restrict__ Wv,
                                             u16* __restrict__ WvT,
                                             const float* __restrict__ Wc,
                                             u16* __restrict__ WcT) {
  __shared__ float tile[32][33];
  int z = blockIdx.z;
  const float* W; u16* WT; int K, N;
  if (z == 0) { W = Wv; WT = WvT; K = 1024; N = 2048; }
  else        { W = Wc; WT = WcT; K = 2048; N = 1024; }
  int n0 = blockIdx.x * 32, k0 = blockIdx.y * 32;
  if (n0 >= N || k0 >= K) return;
  int tx = threadIdx.x & 31, ty = threadIdx.x >> 5;
#pragma unroll
  for (int p = 0; p < 4; ++p)
    tile[ty + 8 * p][tx] = W[(size_t)(k0 + ty + 8 * p) * N + n0 + tx];
  __syncthreads();
#pragma unroll
  for (int p = 0; p < 4; ++p)
    WT[(size_t)(n0 + ty + 8 * p) * K + k0 + tx] = f2bf(tile[tx][ty + 8 * p]);
}

// ---------------- concat four 1024-float biases (biasq|biask contiguous) ------
__global__ __launch_bounds__(256) void bias2_concat(const float* __restrict__ bq1,
                                                    const float* __restrict__ bq2,
                                                    const float* __restrict__ bk1,
                                                    const float* __restrict__ bk2,
                                                    float* __restrict__ out) {
  int i = blockIdx.x * 256 + threadIdx.x;  // 0..4095
  const float* src;
  int j;
  if (i < 1024) { src = bq1; j = i; }
  else if (i < 2048) { src = bq2; j = i - 1024; }
  else if (i < 3072) { src = bk1; j = i - 2048; }
  else { src = bk2; j = i - 3072; }
  out[i] = src[j];
}

// ---------------- GEMM: C[M][N] = A[M][K] @ BT[N][K]^T + bias ----------------
// m97 geometry: 128x128 tile, BK=64, 4 waves, global_load_lds width 16.
// EPI 5 (fused q|k|v, N=2048): rows<4096 -> bf16 q1q2[M][2048];
//   rows 4096..8191 -> kT[((b*2+stream)*16+h)][t][d] at Cv+8388608;
//   rows >=8192 -> vvT ((b*2048+col)*2048+t) at Cv+16777216, bias from biasV.
#define BM 128
#define BN 128
#define BK 64

template <int EPI>
__global__ __launch_bounds__(256) void gemm_bt(const u16* __restrict__ A,
                                               const u16* __restrict__ BT,
                                               const float* __restrict__ bias,
                                               const float* __restrict__ biasV,
                                               void* __restrict__ Cv,
                                               int M, int N, int K) {
  __shared__ __align__(16) u16 As[BM * BK];
  __shared__ __align__(16) u16 Bs[BN * BK];
  int t = threadIdx.x;
  int w = t >> 6, l = t & 63;
  int g = l >> 4, c16 = l & 15;
  int wr = w >> 1, wc = w & 1;
  size_t gm = (size_t)blockIdx.y * BM, gn = (size_t)blockIdx.x * BN;
  if (EPI == 5) {
    if (gm >= 8192) {
      BT += (size_t)4096 * 1024;  // WvT after Wk12T
      bias = biasV;               // bv (f32 device input), no offset
    } else if (gm >= 4096) {
      BT += (size_t)2048 * 1024;  // Wk12T after Wq12T
      bias += 2048;               // biask after biasq
    }
  }

  f32x4 acc[4][4] = {};

  int srow = l >> 3;       // 0..7 (8 lanes per row, 8 elems each)
  int scol = (l & 7) * 8;  // 0..56
  const u16* Ag = A + (gm + w * 32 + srow) * (size_t)K + scol;
  const u16* Bg = BT + (gn + w * 32 + srow) * (size_t)K + scol;

  for (int kt = 0; kt < K; kt += BK) {
    __syncthreads();
#pragma unroll
    for (int c = 0; c < 4; ++c) {
      __builtin_amdgcn_global_load_lds(
          (const __attribute__((address_space(1))) void*)(Ag + (size_t)(c * 8) * K + kt),
          (__attribute__((address_space(3))) void*)&As[(w * 32 + c * 8) * BK], 16, 0, 0);
      __builtin_amdgcn_global_load_lds(
          (const __attribute__((address_space(1))) void*)(Bg + (size_t)(c * 8) * K + kt),
          (__attribute__((address_space(3))) void*)&Bs[(w * 32 + c * 8) * BK], 16, 0, 0);
    }
    __syncthreads();
#pragma unroll
    for (int kk = 0; kk < 2; ++kk) {
      short8 af[4], bf[4];
#pragma unroll
      for (int m = 0; m < 4; ++m)
        af[m] = *reinterpret_cast<const short8*>(
            &As[(wr * 64 + m * 16 + c16) * BK + kk * 32 + g * 8]);
#pragma unroll
      for (int n = 0; n < 4; ++n)
        bf[n] = *reinterpret_cast<const short8*>(
            &Bs[(wc * 64 + n * 16 + c16) * BK + kk * 32 + g * 8]);
#pragma unroll
      for (int m = 0; m < 4; ++m)
#pragma unroll
        for (int n = 0; n < 4; ++n)
          acc[m][n] = mfma16(af[m], bf[n], acc[m][n]);
    }
  }

#pragma unroll
  for (int m = 0; m < 4; ++m)
#pragma unroll
    for (int n = 0; n < 4; ++n) {
      int row0 = (int)gm + wr * 64 + m * 16 + g * 4;
      int col = (int)gn + wc * 64 + n * 16 + c16;
      float bz = bias[col];
      {  // EPI == 5: fused q|k|v
        u16* C = (u16*)Cv;
        if (row0 < 4096) {
#pragma unroll
          for (int r = 0; r < 4; ++r)
            C[(size_t)(row0 + r) * N + col] = f2bf(acc[m][n][r] + bz);
        } else if (row0 < 8192) {
          int t0 = row0 - 4096;
          int bb = t0 >> 11, tt = t0 & 2047;
          int str = col >> 10, hh = (col >> 6) & 15, dd = col & 63;
          u16* KT = C + 8388608;
          size_t base = (((size_t)(bb * 2 + str) * 16 + hh) * 2048 + tt) * (size_t)64 + dd;
#pragma unroll
          for (int r = 0; r < 4; ++r) KT[base + (size_t)r * 64] = f2bf(acc[m][n][r] + bz);
        } else {
          int t0 = row0 - 8192;
          int bb = t0 >> 11, tt = t0 & 2047;
          u16* VT = C + 16777216;
          union { u16 u[4]; uint2 v; } pk;
#pragma unroll
          for (int r = 0; r < 4; ++r) pk.u[r] = f2bf(acc[m][n][r] + bz);
          *reinterpret_cast<uint2*>(&VT[((size_t)(bb * 2048 + col)) * 2048 + tt]) = pk.v;
        }
      }
    }
}

// -------- final GEMM: 128x64 tile (512 blocks = 2/CU), f32 output --------
// block 256 = 4 waves; wave w owns rows [w*32, +32) x all 64 cols; acc[2][4].
#define BMf 128
#define BNf 64
__global__ __launch_bounds__(256) void gemm_fin(const u16* __restrict__ A,
                                                const u16* __restrict__ BT,
                                                const float* __restrict__ bias,
                                                float* __restrict__ C,
                                                int M, int N, int K) {
  __shared__ __align__(16) u16 As[BMf * BK];
  __shared__ __align__(16) u16 Bs[BNf * BK];
  int t = threadIdx.x;
  int w = t >> 6, l = t & 63;
  int g = l >> 4, c16 = l & 15;
  size_t gm = (size_t)blockIdx.y * BMf, gn = (size_t)blockIdx.x * BNf;

  f32x4 acc[2][4] = {};

  int srow = l >> 3;       // 0..7
  int scol = (l & 7) * 8;  // 0..56
  const u16* Ag = A + (gm + w * 32 + srow) * (size_t)K + scol;
  const u16* Bg = BT + (gn + w * 16 + srow) * (size_t)K + scol;

  for (int kt = 0; kt < K; kt += BK) {
    __syncthreads();
#pragma unroll
    for (int c = 0; c < 4; ++c)
      __builtin_amdgcn_global_load_lds(
          (const __attribute__((address_space(1))) void*)(Ag + (size_t)(c * 8) * K + kt),
          (__attribute__((address_space(3))) void*)&As[(w * 32 + c * 8) * BK], 16, 0, 0);
#pragma unroll
    for (int c = 0; c < 2; ++c)
      __builtin_amdgcn_global_load_lds(
          (const __attribute__((address_space(1))) void*)(Bg + (size_t)(c * 8) * K + kt),
          (__attribute__((address_space(3))) void*)&Bs[(w * 16 + c * 8) * BK], 16, 0, 0);
    __syncthreads();
#pragma unroll
    for (int kk = 0; kk < 2; ++kk) {
      short8 af[2], bf[4];
#pragma unroll
      for (int m = 0; m < 2; ++m)
        af[m] = *reinterpret_cast<const short8*>(
            &As[(w * 32 + m * 16 + c16) * BK + kk * 32 + g * 8]);
#pragma unroll
      for (int n = 0; n < 4; ++n)
        bf[n] = *reinterpret_cast<const short8*>(
            &Bs[(n * 16 + c16) * BK + kk * 32 + g * 8]);
#pragma unroll
      for (int m = 0; m < 2; ++m)
#pragma unroll
        for (int n = 0; n < 4; ++n)
          acc[m][n] = mfma16(af[m], bf[n], acc[m][n]);
    }
  }

#pragma unroll
  for (int m = 0; m < 2; ++m)
#pragma unroll
    for (int n = 0; n < 4; ++n) {
      int row0 = (int)gm + w * 32 + m * 16 + g * 4;
      int col = (int)gn + n * 16 + c16;
      float bz = bias[col];
#pragma unroll
      for (int r = 0; r < 4; ++r)
        C[(size_t)(row0 + r) * N + col] = acc[m][n][r] + bz;
    }
}

// ---------------- differential flash attention + fused LN (32x32 swapped) ----
// grid 1024 (1D, XCD-swizzled), block 256 = 4 waves = 2 pairs.
// Pair p covers q-rows [xblk*64 + p*32, +32); wave stream s handles stream s+1.
// 64-key staged tiles, 2-barrier R8/R12-proven staging, COALESCED sources:
// K from kT (contiguous 8KB/stream/tile), V along t (64B/thread contiguous).
#define KROW 72   // K/V LDS row: 64 elems + 8 pad (144B)
#define YROW 72
__global__ __launch_bounds__(256, 3) void diffattn(
    const u16* __restrict__ q1q2, const u16* __restrict__ kT,
    const u16* __restrict__ vvT, const int* __restrict__ mask,
    const float* __restrict__ lq1, const float* __restrict__ lk1,
    const float* __restrict__ lq2, const float* __restrict__ lk2,
    const float* __restrict__ lnw, const float* __restrict__ lnb,
    u16* __restrict__ yout) {
  // Ks [128 rows = stream*64+key][KROW] = 9216 ; Vs [128 d-rows][KROW] = 9216
  __shared__ __align__(16) u16 smem[18432];
  u16* Ksm = smem;
  u16* Vsm = smem + 9216;
  u16* Ysm = smem;  // epilogue overlay

  int tid = threadIdx.x;
  int w = tid >> 6, l = tid & 63;
  int q = l & 31, hi = l >> 5;
  int pair = w >> 1, stream = w & 1;

  // XCD swizzle: same-(b,h) q-blocks land on one XCD -> K/V L2-local
  int id = blockIdx.x;            // 0..1023
  int j = id & 7, rest = id >> 3;
  int xblk = rest & 31, ygrp = rest >> 5;
  int bh = ygrp * 8 + j;
  int b = bh >> 4, h = bh & 15;
  int qr0 = xblk * 64 + pair * 32;

  // lambda
  float lm1 = lq1[h * 64 + l] * lk1[h * 64 + l];
  float lm2 = lq2[h * 64 + l] * lk2[h * 64 + l];
#pragma unroll
  for (int o = 32; o; o >>= 1) {
    lm1 += __shfl_xor(lm1, o);
    lm2 += __shfl_xor(lm2, o);
  }
  float lam = __expf(lm1) - __expf(lm2) + LAMBDA_INIT;

  int soff = stream * 1024;
  const u16* qrow = q1q2 + (size_t)(b * T_SEQ + qr0 + q) * 2048 + h * 64 + soff + hi * 8;
  short8 qf[4];
#pragma unroll
  for (int c = 0; c < 4; ++c) qf[c] = ld8(qrow + c * 16);

  // softmax in log2 domain; mask folds into scale (0 -> uniform softmax)
  float scale = (mask[b * T_SEQ + qr0 + q] == 0) ? 0.f : (SM_SCALE * LOG2E);

  float M = -INFINITY, Lp = 0.f;
  f32x16 acc[4] = {};

  // ---- coalesced staging (256 threads, 8 ld8/thread, all contiguous) ----
  // K: per stream, thread t covers 16 contiguous elems at offset t*16 of the
  //    64x64 kT tile (8KB contiguous per tile).
  int koff = tid * 16;                 // 0..4095
  int krw = koff >> 6, kcl = koff & 63;
  const u16* srcK0 = kT + (((size_t)(b * 2 + 0) * 16 + h) * 2048) * 64 + koff;
  const u16* srcK1 = kT + (((size_t)(b * 2 + 1) * 16 + h) * 2048) * 64 + koff;
  u16* dstK0 = &Ksm[krw * KROW + kcl];
  u16* dstK1 = &Ksm[(64 + krw) * KROW + kcl];
  // V: thread t covers 32 contiguous t-elems of d-row (t>>1) at col (t&1)*32.
  int vd0 = tid >> 1, tcol = (tid & 1) * 32;
  const u16* srcV = vvT + ((size_t)(b * 16 + h) * 128 + vd0) * 2048 + tcol;
  u16* dstV = &Vsm[vd0 * KROW + tcol];

  short8 kpa0, kpa1, kpb0, kpb1, vp0, vp1, vp2, vp3;
  kpa0 = ld8(srcK0); kpa1 = ld8(srcK0 + 8);
  kpb0 = ld8(srcK1); kpb1 = ld8(srcK1 + 8);
  vp0 = ld8(srcV); vp1 = ld8(srcV + 8); vp2 = ld8(srcV + 16); vp3 = ld8(srcV + 24);

  for (int kt = 0; kt < T_SEQ; kt += 64) {
    __syncthreads();  // previous tile's reads complete
    st8(dstK0, kpa0); st8(dstK0 + 8, kpa1);
    st8(dstK1, kpb0); st8(dstK1 + 8, kpb1);
    st8(dstV, vp0); st8(dstV + 8, vp1); st8(dstV + 16, vp2); st8(dstV + 24, vp3);
    __syncthreads();  // tile staged
    if (kt + 64 < T_SEQ) {  // prefetch next tile (consumed NEXT iter)
      size_t ko = (size_t)(kt + 64) * 64;
      kpa0 = ld8(srcK0 + ko); kpa1 = ld8(srcK0 + ko + 8);
      kpb0 = ld8(srcK1 + ko); kpb1 = ld8(srcK1 + ko + 8);
      const u16* nv = srcV + kt + 64;
      vp0 = ld8(nv); vp1 = ld8(nv + 8); vp2 = ld8(nv + 16); vp3 = ld8(nv + 24);
    }

#pragma unroll
    for (int st = 0; st < 2; ++st) {
      const u16* kbase = &Ksm[(stream * 64 + st * 32 + q) * KROW + hi * 8];
      short8 kf[4];
#pragma unroll
      for (int c = 0; c < 4; ++c) kf[c] = ld8(kbase + c * 16);

      f32x16 s = {};
#pragma unroll
      for (int c = 0; c < 4; ++c) s = mfma32(kf[c], qf[c], s);

      // tile max: max3-fusable tree + cross-half
      float m0 = fmaxf(fmaxf(s[0], s[1]), s[2]);
      float m1 = fmaxf(fmaxf(s[3], s[4]), s[5]);
      float m2 = fmaxf(fmaxf(s[6], s[7]), s[8]);
      float m3 = fmaxf(fmaxf(s[9], s[10]), s[11]);
      float m4 = fmaxf(fmaxf(s[12], s[13]), s[14]);
      float ma = fmaxf(fmaxf(m0, m1), m2);
      float mb = fmaxf(fmaxf(m3, m4), s[15]);
      float rm = fmaxf(ma, mb);
      rm = fmaxf(rm, __shfl_xor(rm, 32));
      float tm = rm * scale;

      // defer-max (log2 units: 11.5 ~ e^8); M synced across halves
      if (!__all(tm - M <= 11.5f)) {
        float Mn = fmaxf(M, tm);
        float a = exp2f(M - Mn);
        Lp *= a;
#pragma unroll
        for (int d = 0; d < 4; ++d) acc[d] *= a;
        M = Mn;
      }

      // p = exp2(s*scale - M); lane-local partial sum (combined once at end)
      float p[16];
#pragma unroll
      for (int r = 0; r < 16; ++r) p[r] = exp2f(__builtin_fmaf(s[r], scale, -M));
      float s8[8], s4[4];
#pragma unroll
      for (int i = 0; i < 8; ++i) s8[i] = p[i] + p[i + 8];
#pragma unroll
      for (int i = 0; i < 4; ++i) s4[i] = s8[i] + s8[i + 4];
      Lp += (s4[0] + s4[1]) + (s4[2] + s4[3]);

      // P^T B-frags in-register
      uint32_t a1 = cvtpk(p[0], p[1]), a2 = cvtpk(p[2], p[3]);
      uint32_t b1 = cvtpk(p[4], p[5]), b2 = cvtpk(p[6], p[7]);
      uint32_t c1 = cvtpk(p[8], p[9]), c2 = cvtpk(p[10], p[11]);
      uint32_t d1 = cvtpk(p[12], p[13]), d2 = cvtpk(p[14], p[15]);
      uint32_t sa1 = (uint32_t)__shfl_xor((int)a1, 32), sa2 = (uint32_t)__shfl_xor((int)a2, 32);
      uint32_t sb1 = (uint32_t)__shfl_xor((int)b1, 32), sb2 = (uint32_t)__shfl_xor((int)b2, 32);
      uint32_t sc1 = (uint32_t)__shfl_xor((int)c1, 32), sc2 = (uint32_t)__shfl_xor((int)c2, 32);
      uint32_t sd1 = (uint32_t)__shfl_xor((int)d1, 32), sd2 = (uint32_t)__shfl_xor((int)d2, 32);
      union { uint32_t u[4]; short8 s8v; } pu0, pu1;
      pu0.u[0] = hi ? sb1 : a1;  pu0.u[1] = hi ? sb2 : a2;
      pu0.u[2] = hi ? b1 : sa1;  pu0.u[3] = hi ? b2 : sa2;
      pu1.u[0] = hi ? sd1 : c1;  pu1.u[1] = hi ? sd2 : c2;
      pu1.u[2] = hi ? d1 : sc1;  pu1.u[3] = hi ? d2 : sc2;
      short8 pf0 = pu0.s8v, pf1 = pu1.s8v;

#pragma unroll
      for (int d = 0; d < 4; ++d) {
        const u16* vb0 = &Vsm[(d * 32 + q) * KROW + st * 32 + hi * 8];
        short8 vf0 = ld8(vb0);
        short8 vf1 = ld8(vb0 + 16);
        acc[d] = mfma32(vf0, pf0, acc[d]);
        acc[d] = mfma32(vf1, pf1, acc[d]);
      }
    }
  }

  float L = Lp + __shfl_xor(Lp, 32);
  float inv = 1.f / L;
  __syncthreads();  // staging dead -> Ysm overlay safe
  if (stream == 1) {
    u16* yrow = &Ysm[(pair * 64 + l) * YROW];
#pragma unroll
    for (int d = 0; d < 4; ++d) {
      union { uint32_t u[8]; short8 v[2]; } pk;
#pragma unroll
      for (int i = 0; i < 8; ++i)
        pk.u[i] = cvtpk(acc[d][2 * i] * inv, acc[d][2 * i + 1] * inv);
      st8(yrow + d * 16, pk.v[0]);
      st8(yrow + d * 16 + 8, pk.v[1]);
    }
  }
  __syncthreads();
  if (stream == 0) {
    const u16* yrow = &Ysm[(pair * 64 + l) * YROW];
    float y[4][16];
#pragma unroll
    for (int d = 0; d < 4; ++d) {
      short8 y2a = ld8(yrow + d * 16);
      short8 y2b = ld8(yrow + d * 16 + 8);
#pragma unroll
      for (int i = 0; i < 8; ++i) {
        y[d][i] = acc[d][i] * inv - lam * b2f((u16)y2a[i]);
        y[d][8 + i] = acc[d][8 + i] * inv - lam * b2f((u16)y2b[i]);
      }
    }
    float sm = 0.f;
#pragma unroll
    for (int d = 0; d < 4; ++d)
#pragma unroll
      for (int r = 0; r < 16; ++r) sm += y[d][r];
    sm += __shfl_xor(sm, 32);
    float u = sm * (1.f / 128.f);
    float var = 0.f;
#pragma unroll
    for (int d = 0; d < 4; ++d)
#pragma unroll
      for (int r = 0; r < 16; ++r) { float dd = y[d][r] - u; var += dd * dd; }
    var += __shfl_xor(var, 32);
    float rstd = rsqrtf(var * (1.f / 128.f) + 1e-12f);

    size_t orow = (size_t)(b * T_SEQ + qr0 + q) * 2048 + h * 128;
#pragma unroll
    for (int d = 0; d < 4; ++d)
#pragma unroll
      for (int rr = 0; rr < 4; ++rr) {
        int base = d * 32 + 8 * rr + 4 * hi;
        union { u16 u[4]; uint2 v; } o;
#pragma unroll
        for (int i = 0; i < 4; ++i) {
          float yv = (lnw[base + i] * ((y[d][rr * 4 + i] - u) * rstd) + lnb[base + i]) *
                     ONE_MINUS_LI;
          o.u[i] = f2bf(yv);
        }
        *reinterpret_cast<uint2*>(&yout[orow + base]) = o.v;
      }
  }
}

// ---------------- host ----------------
extern "C" void kernel_launch(void* const* d_in, const int* in_sizes, int n_in,
                              void* d_out, int out_size, void* d_ws, size_t ws_size,
                              hipStream_t stream) {
  (void)in_sizes; (void)n_in; (void)out_size; (void)ws_size;
  const float* q   = (const float*)d_in[0];
  const float* k   = (const float*)d_in[1];
  const float* v   = (const float*)d_in[2];
  const int* maskp = (const int*)d_in[3];
  const float* Wq1 = (const float*)d_in[4];
  const float* bq1 = (const float*)d_in[5];
  const float* Wq2 = (const float*)d_in[6];
  const float* bq2 = (const float*)d_in[7];
  const float* Wk1 = (const float*)d_in[8];
  const float* bk1 = (const float*)d_in[9];
  const float* Wk2 = (const float*)d_in[10];
  const float* bk2 = (const float*)d_in[11];
  const float* Wv  = (const float*)d_in[12];
  const float* bv  = (const float*)d_in[13];
  const float* Wc  = (const float*)d_in[14];
  const float* bc  = (const float*)d_in[15];
  const float* lnw = (const float*)d_in[16];
  const float* lnb = (const float*)d_in[17];
  const float* lq1 = (const float*)d_in[18];
  const float* lk1 = (const float*)d_in[19];
  const float* lq2 = (const float*)d_in[20];
  const float* lk2 = (const float*)d_in[21];

  char* ws = (char*)d_ws;
  u16* qb     = (u16*)(ws + 0);          // qb|kb|vb contiguous [12288][1024]
  u16* Wq12T  = (u16*)(ws + 25165824);   // Wq12T|Wk12T|WvT contiguous [6144][1024]
  u16* WvT    = (u16*)(ws + 33554432);
  u16* WcT    = (u16*)(ws + 37748736);
  float* biasq = (float*)(ws + 41943040);  // [4096]: biasq|biask (exactly fits)
  u16* q1q2   = (u16*)(ws + 41959424);   // q1q2|kT|vvT contiguous
  u16* kT     = (u16*)(ws + 58736640);
  u16* vvT    = (u16*)(ws + 75513856);
  u16* yb     = (u16*)(ws + 0);  // alias qb+kb (16MB; both dead before attention)

  const int NELEM = 2 * T_SEQ * 1024;  // 4,194,304

  cvt3_bf16<<<12288, 256, 0, stream>>>(q, k, v, qb, NELEM);

  tcvt4<<<dim3(32, 32, 4), 256, 0, stream>>>(Wq1, Wq2, Wk1, Wk2, Wq12T);
  tcvt2<<<dim3(64, 64, 2), 256, 0, stream>>>(Wv, WvT, Wc, WcT);

  bias2_concat<<<16, 256, 0, stream>>>(bq1, bq2, bk1, bk2, biasq);

  // ONE projection GEMM: M=12288 over qb|kb|vb; epilogues q1q2 / kT / vvT
  gemm_bt<5><<<dim3(16, 96), 256, 0, stream>>>(qb, Wq12T, biasq, bv, q1q2,
                                               12288, 2048, 1024);

  diffattn<<<1024, 256, 0, stream>>>(q1q2, kT, vvT, maskp,
                                     lq1, lk1, lq2, lk2, lnw, lnb, yb);

  // final GEMM: 128x64 tile, 512 blocks = 2/CU
  gemm_fin<<<dim3(16, 32), 256, 0, stream>>>(yb, WcT, bc, (float*)d_out,
                                             4096, 1024, 2048);
}

// Round 22
// 301.749 us; speedup vs baseline: 1.4338x; 1.0060x over previous
//
#include <hip/hip_runtime.h>
#include <hip/hip_bf16.h>
#include <stdint.h>

// MultiHeadDiffAttention — R22 = R21 (303.6us) + dispatch consolidation:
// tcvt6 (all 6 weight transposes, one 1D launch) and bias folded into the
// projection-GEMM epilogue (1024-boundary is block-uniform at BN=128).
// Launches 7 -> 5. diffattn byte-identical to R17-R21 (regalloc knife-edge;
// occupancy forensics: 148 unified regs -> 3 blk/CU, 1024=768+256 ragged ->
// measured 25% avg; unfixable without K-split 2-pass, EV-negative).
// B=2, T=2048, C=1024, H=16, HS=64.

#define T_SEQ 2048

typedef unsigned short u16;
typedef __attribute__((ext_vector_type(8))) short short8;
typedef __attribute__((ext_vector_type(4))) float f32x4;
typedef __attribute__((ext_vector_type(16))) float f32x16;

#define LAMBDA_INIT 0.35550906759096926f
#define ONE_MINUS_LI 0.6444909324090307f
#define SM_SCALE 0.125f
#define LOG2E 1.44269504f

__device__ __forceinline__ u16 f2bf(float f) {
  uint32_t u = __float_as_uint(f);
  return (u16)((u + 0x7FFFu + ((u >> 16) & 1u)) >> 16);
}
__device__ __forceinline__ float b2f(u16 u) {
  return __uint_as_float(((uint32_t)u) << 16);
}
__device__ __forceinline__ short8 ld8(const u16* p) {
  return *reinterpret_cast<const short8*>(p);
}
__device__ __forceinline__ void st8(u16* p, short8 v) {
  *reinterpret_cast<short8*>(p) = v;
}
__device__ __forceinline__ f32x4 mfma16(short8 a, short8 b, f32x4 c) {
  return __builtin_amdgcn_mfma_f32_16x16x32_bf16(a, b, c, 0, 0, 0);
}
__device__ __forceinline__ f32x16 mfma32(short8 a, short8 b, f32x16 c) {
  return __builtin_amdgcn_mfma_f32_32x32x16_bf16(a, b, c, 0, 0, 0);
}
__device__ __forceinline__ uint32_t cvtpk(float lo, float hi_) {
  uint32_t r;
  asm("v_cvt_pk_bf16_f32 %0, %1, %2" : "=v"(r) : "v"(lo), "v"(hi_));
  return r;
}

// ------------- merged elementwise f32 -> bf16 (q,k,v in one launch) -------------
__global__ __launch_bounds__(256) void cvt3_bf16(const float* __restrict__ q,
                                                 const float* __restrict__ k,
                                                 const float* __restrict__ v,
                                                 u16* __restrict__ out, int n) {
  int i = (blockIdx.x * 256 + threadIdx.x) * 4;  // over 3n elems
  const float* src;
  int j = i;
  if (i < n) src = q;
  else if (i < 2 * n) { src = k; j = i - n; }
  else { src = v; j = i - 2 * n; }
  float4 f = *reinterpret_cast<const float4*>(src + j);
  union { u16 u[4]; uint2 v2; } pk;
  pk.u[0] = f2bf(f.x); pk.u[1] = f2bf(f.y); pk.u[2] = f2bf(f.z); pk.u[3] = f2bf(f.w);
  *reinterpret_cast<uint2*>(out + i) = pk.v2;
}

// ----- tcvt6: all six weight transposes in ONE 1D launch (8192 blocks) -----
// id<4096: four 1024x1024 (Wq1,Wq2,Wk1,Wk2 -> WqkT rows z*1024)
// id<6144: Wv 1024x2048 -> WvT ; else: Wc 2048x1024 -> WcT
__global__ __launch_bounds__(256) void tcvt6(const float* __restrict__ W0,
                                             const float* __restrict__ W1,
                                             const float* __restrict__ W2,
                                             const float* __restrict__ W3,
                                             const float* __restrict__ Wv,
                                             const float* __restrict__ Wc,
                                             u16* __restrict__ WqkT,
                                             u16* __restrict__ WvT,
                                             u16* __restrict__ WcT) {
  __shared__ float tile[32][33];
  int id = blockIdx.x;
  const float* W; u16* WT; int K, N, n0, k0, outRowOff;
  if (id < 4096) {
    int z = id >> 10, r = id & 1023;
    W = (z == 0) ? W0 : (z == 1) ? W1 : (z == 2) ? W2 : W3;
    WT = WqkT; K = 1024; N = 1024;
    n0 = (r & 31) * 32; k0 = (r >> 5) * 32; outRowOff = z * 1024;
  } else if (id < 6144) {
    int r = id - 4096;
    W = Wv; WT = WvT; K = 1024; N = 2048;
    n0 = (r & 63) * 32; k0 = (r >> 6) * 32; outRowOff = 0;
  } else {
    int r = id - 6144;
    W = Wc; WT = WcT; K = 2048; N = 1024;
    n0 = (r & 31) * 32; k0 = (r >> 5) * 32; outRowOff = 0;
  }
  int tx = threadIdx.x & 31, ty = threadIdx.x >> 5;
#pragma unroll
  for (int p = 0; p < 4; ++p)
    tile[ty + 8 * p][tx] = W[(size_t)(k0 + ty + 8 * p) * N + n0 + tx];
  __syncthreads();
#pragma unroll
  for (int p = 0; p < 4; ++p)
    WT[(size_t)(outRowOff + n0 + ty + 8 * p) * K + k0 + tx] = f2bf(tile[tx][ty + 8 * p]);
}

// ---------------- GEMM: C[M][N] = A[M][K] @ BT[N][K]^T + bias ----------------
// m97 geometry: 128x128 tile, BK=64, 4 waves, global_load_lds width 16.
// EPI 5 (fused q|k|v, N=2048): rows<4096 -> bf16 q1q2[M][2048];
//   rows 4096..8191 -> kT[((b*2+stream)*16+h)][t][d] at Cv+8388608;
//   rows >=8192 -> vvT ((b*2048+col)*2048+t) at Cv+16777216.
// Bias read directly from the four 1024-f32 inputs + bv (block-uniform select:
// BN=128 blocks never straddle the 1024 column boundary).
#define BM 128
#define BN 128
#define BK 64

__global__ __launch_bounds__(256) void gemm_proj(const u16* __restrict__ A,
                                                 const u16* __restrict__ BT,
                                                 const float* __restrict__ bq1,
                                                 const float* __restrict__ bq2,
                                                 const float* __restrict__ bk1,
                                                 const float* __restrict__ bk2,
                                                 const float* __restrict__ bv,
                                                 void* __restrict__ Cv,
                                                 int M, int N, int K) {
  __shared__ __align__(16) u16 As[BM * BK];
  __shared__ __align__(16) u16 Bs[BN * BK];
  int t = threadIdx.x;
  int w = t >> 6, l = t & 63;
  int g = l >> 4, c16 = l & 15;
  int wr = w >> 1, wc = w & 1;
  size_t gm = (size_t)blockIdx.y * BM, gn = (size_t)blockIdx.x * BN;
  const float* pA;
  const float* pB;
  if (gm >= 8192) {
    BT += (size_t)4096 * 1024;  // WvT after Wk12T
    pA = bv; pB = bv + 1024;
  } else if (gm >= 4096) {
    BT += (size_t)2048 * 1024;  // Wk12T after Wq12T
    pA = bk1; pB = bk2;
  } else {
    pA = bq1; pB = bq2;
  }
  const float* bp = (gn < 1024) ? pA : (pB - 1024);  // block-uniform

  f32x4 acc[4][4] = {};

  int srow = l >> 3;       // 0..7 (8 lanes per row, 8 elems each)
  int scol = (l & 7) * 8;  // 0..56
  const u16* Ag = A + (gm + w * 32 + srow) * (size_t)K + scol;
  const u16* Bg = BT + (gn + w * 32 + srow) * (size_t)K + scol;

  for (int kt = 0; kt < K; kt += BK) {
    __syncthreads();
#pragma unroll
    for (int c = 0; c < 4; ++c) {
      __builtin_amdgcn_global_load_lds(
          (const __attribute__((address_space(1))) void*)(Ag + (size_t)(c * 8) * K + kt),
          (__attribute__((address_space(3))) void*)&As[(w * 32 + c * 8) * BK], 16, 0, 0);
      __builtin_amdgcn_global_load_lds(
          (const __attribute__((address_space(1))) void*)(Bg + (size_t)(c * 8) * K + kt),
          (__attribute__((address_space(3))) void*)&Bs[(w * 32 + c * 8) * BK], 16, 0, 0);
    }
    __syncthreads();
#pragma unroll
    for (int kk = 0; kk < 2; ++kk) {
      short8 af[4], bf[4];
#pragma unroll
      for (int m = 0; m < 4; ++m)
        af[m] = *reinterpret_cast<const short8*>(
            &As[(wr * 64 + m * 16 + c16) * BK + kk * 32 + g * 8]);
#pragma unroll
      for (int n = 0; n < 4; ++n)
        bf[n] = *reinterpret_cast<const short8*>(
            &Bs[(wc * 64 + n * 16 + c16) * BK + kk * 32 + g * 8]);
#pragma unroll
      for (int m = 0; m < 4; ++m)
#pragma unroll
        for (int n = 0; n < 4; ++n)
          acc[m][n] = mfma16(af[m], bf[n], acc[m][n]);
    }
  }

#pragma unroll
  for (int m = 0; m < 4; ++m)
#pragma unroll
    for (int n = 0; n < 4; ++n) {
      int row0 = (int)gm + wr * 64 + m * 16 + g * 4;
      int col = (int)gn + wc * 64 + n * 16 + c16;
      float bz = bp[col];
      u16* C = (u16*)Cv;
      if (row0 < 4096) {
#pragma unroll
        for (int r = 0; r < 4; ++r)
          C[(size_t)(row0 + r) * N + col] = f2bf(acc[m][n][r] + bz);
      } else if (row0 < 8192) {
        int t0 = row0 - 4096;
        int bb = t0 >> 11, tt = t0 & 2047;
        int str = col >> 10, hh = (col >> 6) & 15, dd = col & 63;
        u16* KT = C + 8388608;
        size_t base = (((size_t)(bb * 2 + str) * 16 + hh) * 2048 + tt) * (size_t)64 + dd;
#pragma unroll
        for (int r = 0; r < 4; ++r) KT[base + (size_t)r * 64] = f2bf(acc[m][n][r] + bz);
      } else {
        int t0 = row0 - 8192;
        int bb = t0 >> 11, tt = t0 & 2047;
        u16* VT = C + 16777216;
        union { u16 u[4]; uint2 v; } pk;
#pragma unroll
        for (int r = 0; r < 4; ++r) pk.u[r] = f2bf(acc[m][n][r] + bz);
        *reinterpret_cast<uint2*>(&VT[((size_t)(bb * 2048 + col)) * 2048 + tt]) = pk.v;
      }
    }
}

// -------- final GEMM: 128x64 tile (512 blocks = 2/CU), f32 output --------
#define BMf 128
#define BNf 64
__global__ __launch_bounds__(256) void gemm_fin(const u16* __restrict__ A,
                                                const u16* __restrict__ BT,
                                                const float* __restrict__ bias,
                                                float* __restrict__ C,
                                                int M, int N, int K) {
  __shared__ __align__(16) u16 As[BMf * BK];
  __shared__ __align__(16) u16 Bs[BNf * BK];
  int t = threadIdx.x;
  int w = t >> 6, l = t & 63;
  int g = l >> 4, c16 = l & 15;
  size_t gm = (size_t)blockIdx.y * BMf, gn = (size_t)blockIdx.x * BNf;

  f32x4 acc[2][4] = {};

  int srow = l >> 3;       // 0..7
  int scol = (l & 7) * 8;  // 0..56
  const u16* Ag = A + (gm + w * 32 + srow) * (size_t)K + scol;
  const u16* Bg = BT + (gn + w * 16 + srow) * (size_t)K + scol;

  for (int kt = 0; kt < K; kt += BK) {
    __syncthreads();
#pragma unroll
    for (int c = 0; c < 4; ++c)
      __builtin_amdgcn_global_load_lds(
          (const __attribute__((address_space(1))) void*)(Ag + (size_t)(c * 8) * K + kt),
          (__attribute__((address_space(3))) void*)&As[(w * 32 + c * 8) * BK], 16, 0, 0);
#pragma unroll
    for (int c = 0; c < 2; ++c)
      __builtin_amdgcn_global_load_lds(
          (const __attribute__((address_space(1))) void*)(Bg + (size_t)(c * 8) * K + kt),
          (__attribute__((address_space(3))) void*)&Bs[(w * 16 + c * 8) * BK], 16, 0, 0);
    __syncthreads();
#pragma unroll
    for (int kk = 0; kk < 2; ++kk) {
      short8 af[2], bf[4];
#pragma unroll
      for (int m = 0; m < 2; ++m)
        af[m] = *reinterpret_cast<const short8*>(
            &As[(w * 32 + m * 16 + c16) * BK + kk * 32 + g * 8]);
#pragma unroll
      for (int n = 0; n < 4; ++n)
        bf[n] = *reinterpret_cast<const short8*>(
            &Bs[(n * 16 + c16) * BK + kk * 32 + g * 8]);
#pragma unroll
      for (int m = 0; m < 2; ++m)
#pragma unroll
        for (int n = 0; n < 4; ++n)
          acc[m][n] = mfma16(af[m], bf[n], acc[m][n]);
    }
  }

#pragma unroll
  for (int m = 0; m < 2; ++m)
#pragma unroll
    for (int n = 0; n < 4; ++n) {
      int row0 = (int)gm + w * 32 + m * 16 + g * 4;
      int col = (int)gn + n * 16 + c16;
      float bz = bias[col];
#pragma unroll
      for (int r = 0; r < 4; ++r)
        C[(size_t)(row0 + r) * N + col] = acc[m][n][r] + bz;
    }
}

// ---------------- differential flash attention + fused LN (32x32 swapped) ----
// grid 1024 (1D, XCD-swizzled), block 256 = 4 waves = 2 pairs.
// Pair p covers q-rows [xblk*64 + p*32, +32); wave stream s handles stream s+1.
// 64-key staged tiles, 2-barrier R8/R12-proven staging, COALESCED sources:
// K from kT (contiguous 8KB/stream/tile), V along t (64B/thread contiguous).
#define KROW 72   // K/V LDS row: 64 elems + 8 pad (144B)
#define YROW 72
__global__ __launch_bounds__(256, 3) void diffattn(
    const u16* __restrict__ q1q2, const u16* __restrict__ kT,
    const u16* __restrict__ vvT, const int* __restrict__ mask,
    const float* __restrict__ lq1, const float* __restrict__ lk1,
    const float* __restrict__ lq2, const float* __restrict__ lk2,
    const float* __restrict__ lnw, const float* __restrict__ lnb,
    u16* __restrict__ yout) {
  // Ks [128 rows = stream*64+key][KROW] = 9216 ; Vs [128 d-rows][KROW] = 9216
  __shared__ __align__(16) u16 smem[18432];
  u16* Ksm = smem;
  u16* Vsm = smem + 9216;
  u16* Ysm = smem;  // epilogue overlay

  int tid = threadIdx.x;
  int w = tid >> 6, l = tid & 63;
  int q = l & 31, hi = l >> 5;
  int pair = w >> 1, stream = w & 1;

  // XCD swizzle: same-(b,h) q-blocks land on one XCD -> K/V L2-local
  int id = blockIdx.x;            // 0..1023
  int j = id & 7, rest = id >> 3;
  int xblk = rest & 31, ygrp = rest >> 5;
  int bh = ygrp * 8 + j;
  int b = bh >> 4, h = bh & 15;
  int qr0 = xblk * 64 + pair * 32;

  // lambda
  float lm1 = lq1[h * 64 + l] * lk1[h * 64 + l];
  float lm2 = lq2[h * 64 + l] * lk2[h * 64 + l];
#pragma unroll
  for (int o = 32; o; o >>= 1) {
    lm1 += __shfl_xor(lm1, o);
    lm2 += __shfl_xor(lm2, o);
  }
  float lam = __expf(lm1) - __expf(lm2) + LAMBDA_INIT;

  int soff = stream * 1024;
  const u16* qrow = q1q2 + (size_t)(b * T_SEQ + qr0 + q) * 2048 + h * 64 + soff + hi * 8;
  short8 qf[4];
#pragma unroll
  for (int c = 0; c < 4; ++c) qf[c] = ld8(qrow + c * 16);

  // softmax in log2 domain; mask folds into scale (0 -> uniform softmax)
  float scale = (mask[b * T_SEQ + qr0 + q] == 0) ? 0.f : (SM_SCALE * LOG2E);

  float M = -INFINITY, Lp = 0.f;
  f32x16 acc[4] = {};

  // ---- coalesced staging (256 threads, 8 ld8/thread, all contiguous) ----
  // K: per stream, thread t covers 16 contiguous elems at offset t*16 of the
  //    64x64 kT tile (8KB contiguous per tile).
  int koff = tid * 16;                 // 0..4095
  int krw = koff >> 6, kcl = koff & 63;
  const u16* srcK0 = kT + (((size_t)(b * 2 + 0) * 16 + h) * 2048) * 64 + koff;
  const u16* srcK1 = kT + (((size_t)(b * 2 + 1) * 16 + h) * 2048) * 64 + koff;
  u16* dstK0 = &Ksm[krw * KROW + kcl];
  u16* dstK1 = &Ksm[(64 + krw) * KROW + kcl];
  // V: thread t covers 32 contiguous t-elems of d-row (t>>1) at col (t&1)*32.
  int vd0 = tid >> 1, tcol = (tid & 1) * 32;
  const u16* srcV = vvT + ((size_t)(b * 16 + h) * 128 + vd0) * 2048 + tcol;
  u16* dstV = &Vsm[vd0 * KROW + tcol];

  short8 kpa0, kpa1, kpb0, kpb1, vp0, vp1, vp2, vp3;
  kpa0 = ld8(srcK0); kpa1 = ld8(srcK0 + 8);
  kpb0 = ld8(srcK1); kpb1 = ld8(srcK1 + 8);
  vp0 = ld8(srcV); vp1 = ld8(srcV + 8); vp2 = ld8(srcV + 16); vp3 = ld8(srcV + 24);

  for (int kt = 0; kt < T_SEQ; kt += 64) {
    __syncthreads();  // previous tile's reads complete
    st8(dstK0, kpa0); st8(dstK0 + 8, kpa1);
    st8(dstK1, kpb0); st8(dstK1 + 8, kpb1);
    st8(dstV, vp0); st8(dstV + 8, vp1); st8(dstV + 16, vp2); st8(dstV + 24, vp3);
    __syncthreads();  // tile staged
    if (kt + 64 < T_SEQ) {  // prefetch next tile (consumed NEXT iter)
      size_t ko = (size_t)(kt + 64) * 64;
      kpa0 = ld8(srcK0 + ko); kpa1 = ld8(srcK0 + ko + 8);
      kpb0 = ld8(srcK1 + ko); kpb1 = ld8(srcK1 + ko + 8);
      const u16* nv = srcV + kt + 64;
      vp0 = ld8(nv); vp1 = ld8(nv + 8); vp2 = ld8(nv + 16); vp3 = ld8(nv + 24);
    }

#pragma unroll
    for (int st = 0; st < 2; ++st) {
      const u16* kbase = &Ksm[(stream * 64 + st * 32 + q) * KROW + hi * 8];
      short8 kf[4];
#pragma unroll
      for (int c = 0; c < 4; ++c) kf[c] = ld8(kbase + c * 16);

      f32x16 s = {};
#pragma unroll
      for (int c = 0; c < 4; ++c) s = mfma32(kf[c], qf[c], s);

      // tile max: max3-fusable tree + cross-half
      float m0 = fmaxf(fmaxf(s[0], s[1]), s[2]);
      float m1 = fmaxf(fmaxf(s[3], s[4]), s[5]);
      float m2 = fmaxf(fmaxf(s[6], s[7]), s[8]);
      float m3 = fmaxf(fmaxf(s[9], s[10]), s[11]);
      float m4 = fmaxf(fmaxf(s[12], s[13]), s[14]);
      float ma = fmaxf(fmaxf(m0, m1), m2);
      float mb = fmaxf(fmaxf(m3, m4), s[15]);
      float rm = fmaxf(ma, mb);
      rm = fmaxf(rm, __shfl_xor(rm, 32));
      float tm = rm * scale;

      // defer-max (log2 units: 11.5 ~ e^8); M synced across halves
      if (!__all(tm - M <= 11.5f)) {
        float Mn = fmaxf(M, tm);
        float a = exp2f(M - Mn);
        Lp *= a;
#pragma unroll
        for (int d = 0; d < 4; ++d) acc[d] *= a;
        M = Mn;
      }

      // p = exp2(s*scale - M); lane-local partial sum (combined once at end)
      float p[16];
#pragma unroll
      for (int r = 0; r < 16; ++r) p[r] = exp2f(__builtin_fmaf(s[r], scale, -M));
      float s8[8], s4[4];
#pragma unroll
      for (int i = 0; i < 8; ++i) s8[i] = p[i] + p[i + 8];
#pragma unroll
      for (int i = 0; i < 4; ++i) s4[i] = s8[i] + s8[i + 4];
      Lp += (s4[0] + s4[1]) + (s4[2] + s4[3]);

      // P^T B-frags in-register
      uint32_t a1 = cvtpk(p[0], p[1]), a2 = cvtpk(p[2], p[3]);
      uint32_t b1 = cvtpk(p[4], p[5]), b2 = cvtpk(p[6], p[7]);
      uint32_t c1 = cvtpk(p[8], p[9]), c2 = cvtpk(p[10], p[11]);
      uint32_t d1 = cvtpk(p[12], p[13]), d2 = cvtpk(p[14], p[15]);
      uint32_t sa1 = (uint32_t)__shfl_xor((int)a1, 32), sa2 = (uint32_t)__shfl_xor((int)a2, 32);
      uint32_t sb1 = (uint32_t)__shfl_xor((int)b1, 32), sb2 = (uint32_t)__shfl_xor((int)b2, 32);
      uint32_t sc1 = (uint32_t)__shfl_xor((int)c1, 32), sc2 = (uint32_t)__shfl_xor((int)c2, 32);
      uint32_t sd1 = (uint32_t)__shfl_xor((int)d1, 32), sd2 = (uint32_t)__shfl_xor((int)d2, 32);
      union { uint32_t u[4]; short8 s8v; } pu0, pu1;
      pu0.u[0] = hi ? sb1 : a1;  pu0.u[1] = hi ? sb2 : a2;
      pu0.u[2] = hi ? b1 : sa1;  pu0.u[3] = hi ? b2 : sa2;
      pu1.u[0] = hi ? sd1 : c1;  pu1.u[1] = hi ? sd2 : c2;
      pu1.u[2] = hi ? d1 : sc1;  pu1.u[3] = hi ? d2 : sc2;
      short8 pf0 = pu0.s8v, pf1 = pu1.s8v;

#pragma unroll
      for (int d = 0; d < 4; ++d) {
        const u16* vb0 = &Vsm[(d * 32 + q) * KROW + st * 32 + hi * 8];
        short8 vf0 = ld8(vb0);
        short8 vf1 = ld8(vb0 + 16);
        acc[d] = mfma32(vf0, pf0, acc[d]);
        acc[d] = mfma32(vf1, pf1, acc[d]);
      }
    }
  }

  float L = Lp + __shfl_xor(Lp, 32);
  float inv = 1.f / L;
  __syncthreads();  // staging dead -> Ysm overlay safe
  if (stream == 1) {
    u16* yrow = &Ysm[(pair * 64 + l) * YROW];
#pragma unroll
    for (int d = 0; d < 4; ++d) {
      union { uint32_t u[8]; short8 v[2]; } pk;
#pragma unroll
      for (int i = 0; i < 8; ++i)
        pk.u[i] = cvtpk(acc[d][2 * i] * inv, acc[d][2 * i + 1] * inv);
      st8(yrow + d * 16, pk.v[0]);
      st8(yrow + d * 16 + 8, pk.v[1]);
    }
  }
  __syncthreads();
  if (stream == 0) {
    const u16* yrow = &Ysm[(pair * 64 + l) * YROW];
    float y[4][16];
#pragma unroll
    for (int d = 0; d < 4; ++d) {
      short8 y2a = ld8(yrow + d * 16);
      short8 y2b = ld8(yrow + d * 16 + 8);
#pragma unroll
      for (int i = 0; i < 8; ++i) {
        y[d][i] = acc[d][i] * inv - lam * b2f((u16)y2a[i]);
        y[d][8 + i] = acc[d][8 + i] * inv - lam * b2f((u16)y2b[i]);
      }
    }
    float sm = 0.f;
#pragma unroll
    for (int d = 0; d < 4; ++d)
#pragma unroll
      for (int r = 0; r < 16; ++r) sm += y[d][r];
    sm += __shfl_xor(sm, 32);
    float u = sm * (1.f / 128.f);
    float var = 0.f;
#pragma unroll
    for (int d = 0; d < 4; ++d)
#pragma unroll
      for (int r = 0; r < 16; ++r) { float dd = y[d][r] - u; var += dd * dd; }
    var += __shfl_xor(var, 32);
    float rstd = rsqrtf(var * (1.f / 128.f) + 1e-12f);

    size_t orow = (size_t)(b * T_SEQ + qr0 + q) * 2048 + h * 128;
#pragma unroll
    for (int d = 0; d < 4; ++d)
#pragma unroll
      for (int rr = 0; rr < 4; ++rr) {
        int base = d * 32 + 8 * rr + 4 * hi;
        union { u16 u[4]; uint2 v; } o;
#pragma unroll
        for (int i = 0; i < 4; ++i) {
          float yv = (lnw[base + i] * ((y[d][rr * 4 + i] - u) * rstd) + lnb[base + i]) *
                     ONE_MINUS_LI;
          o.u[i] = f2bf(yv);
        }
        *reinterpret_cast<uint2*>(&yout[orow + base]) = o.v;
      }
  }
}

// ---------------- host ----------------
extern "C" void kernel_launch(void* const* d_in, const int* in_sizes, int n_in,
                              void* d_out, int out_size, void* d_ws, size_t ws_size,
                              hipStream_t stream) {
  (void)in_sizes; (void)n_in; (void)out_size; (void)ws_size;
  const float* q   = (const float*)d_in[0];
  const float* k   = (const float*)d_in[1];
  const float* v   = (const float*)d_in[2];
  const int* maskp = (const int*)d_in[3];
  const float* Wq1 = (const float*)d_in[4];
  const float* bq1 = (const float*)d_in[5];
  const float* Wq2 = (const float*)d_in[6];
  const float* bq2 = (const float*)d_in[7];
  const float* Wk1 = (const float*)d_in[8];
  const float* bk1 = (const float*)d_in[9];
  const float* Wk2 = (const float*)d_in[10];
  const float* bk2 = (const float*)d_in[11];
  const float* Wv  = (const float*)d_in[12];
  const float* bv  = (const float*)d_in[13];
  const float* Wc  = (const float*)d_in[14];
  const float* bc  = (const float*)d_in[15];
  const float* lnw = (const float*)d_in[16];
  const float* lnb = (const float*)d_in[17];
  const float* lq1 = (const float*)d_in[18];
  const float* lk1 = (const float*)d_in[19];
  const float* lq2 = (const float*)d_in[20];
  const float* lk2 = (const float*)d_in[21];

  char* ws = (char*)d_ws;
  u16* qb     = (u16*)(ws + 0);          // qb|kb|vb contiguous [12288][1024]
  u16* Wq12T  = (u16*)(ws + 25165824);   // Wq12T|Wk12T|WvT contiguous [6144][1024]
  u16* WvT    = (u16*)(ws + 33554432);
  u16* WcT    = (u16*)(ws + 37748736);
  u16* q1q2   = (u16*)(ws + 41959424);   // q1q2|kT|vvT contiguous
  u16* kT     = (u16*)(ws + 58736640);
  u16* vvT    = (u16*)(ws + 75513856);
  u16* yb     = (u16*)(ws + 0);  // alias qb+kb (16MB; both dead before attention)

  const int NELEM = 2 * T_SEQ * 1024;  // 4,194,304

  cvt3_bf16<<<12288, 256, 0, stream>>>(q, k, v, qb, NELEM);

  tcvt6<<<8192, 256, 0, stream>>>(Wq1, Wq2, Wk1, Wk2, Wv, Wc, Wq12T, WvT, WcT);

  // ONE projection GEMM: M=12288 over qb|kb|vb; epilogues q1q2 / kT / vvT
  gemm_proj<<<dim3(16, 96), 256, 0, stream>>>(qb, Wq12T, bq1, bq2, bk1, bk2, bv,
                                              q1q2, 12288, 2048, 1024);

  diffattn<<<1024, 256, 0, stream>>>(q1q2, kT, vvT, maskp,
                                     lq1, lk1, lq2, lk2, lnw, lnb, yb);

  // final GEMM: 128x64 tile, 512 blocks = 2/CU
  gemm_fin<<<dim3(16, 32), 256, 0, stream>>>(yb, WcT, bc, (float*)d_out,
                                             4096, 1024, 2048);
}